// Round 8
// baseline (160.455 us; speedup 1.0000x reference)
//
#include <hip/hip_runtime.h>
#include <hip/hip_bf16.h>
#include <stdint.h>

typedef unsigned short u16;
typedef uint32_t u32;
typedef short s16x8 __attribute__((ext_vector_type(8)));
typedef float f32x4 __attribute__((ext_vector_type(4)));

#define SDIM 2048
#define EDIM 1024

static __device__ __forceinline__ float b2f(u16 v) {
    union { float f; u32 u; } c; c.u = ((u32)v) << 16; return c.f;
}
static __device__ __forceinline__ u16 f2b(float f) {
    union { float f; u32 u; } c; c.f = f;
    u32 u = c.u;
    u32 r = (u + 0x7FFFu + ((u >> 16) & 1u)) >> 16;
    return (u16)r;
}
static __device__ __forceinline__ void gll16(const u16* g, u16* l) {
    __builtin_amdgcn_global_load_lds(
        (const __attribute__((address_space(1))) void*)g,
        (__attribute__((address_space(3))) void*)l, 16, 0, 0);
}

// per-wave dtype sniff (verified R1/R5)
static __device__ __forceinline__ int sniff_bf16(const u16* __restrict__ x) {
    u16 v = x[(threadIdx.x & 63) * 2];
    int e = (v >> 7) & 0xFF;
    unsigned long long m = __ballot(e >= 90 && e <= 144);
    return __popcll(m) >= 48;
}

// ---- fused prep: z=0 Wa^T, z=1 Wp^T (LDS-tiled), z=2 X convert (fp32 path) ----
__global__ __launch_bounds__(256) void k_prep(
    const void* __restrict__ X, const void* __restrict__ Wa,
    const void* __restrict__ Wp, u16* __restrict__ Xb,
    u16* __restrict__ WtA, u16* __restrict__ WtP) {
    int f = sniff_bf16((const u16*)X);
    int z = blockIdx.z;
    int t = threadIdx.x;
    if (z == 2) {
        if (f) return;
        const float* s = (const float*)X;
        int bid = blockIdx.y * 48 + blockIdx.x;
        for (int c = bid; c < 2048; c += 768) {
            long i = ((long)c * 256 + t) * 8;
            u16 o[8];
            for (int j = 0; j < 8; ++j) o[j] = f2b(s[i + j]);
            *(uint4*)&Xb[i] = *(uint4*)o;
        }
        return;
    }
    if (z == 1 && blockIdx.x >= 16) return;
    const void* src = z ? Wp : Wa;
    u16* dst = z ? WtP : WtA;
    int Nsrc = z ? 1024 : 3072;
    int n0 = blockIdx.x * 64, k0 = blockIdx.y * 64;
    __shared__ u16 L[64 * 72];
    int r = t >> 2, c0 = (t & 3) * 16;
    u16 val[16];
    if (f) {
        const u16* s = (const u16*)src + (size_t)(k0 + r) * Nsrc + n0 + c0;
        *(uint4*)&val[0] = *(const uint4*)s;
        *(uint4*)&val[8] = *(const uint4*)(s + 8);
    } else {
        const float* s = (const float*)src + (size_t)(k0 + r) * Nsrc + n0 + c0;
        for (int j = 0; j < 16; ++j) val[j] = f2b(s[j]);
    }
    for (int j = 0; j < 16; ++j) L[(c0 + j) * 72 + r] = val[j];
    __syncthreads();
    uint4 o0 = *(const uint4*)&L[r * 72 + c0];
    uint4 o1 = *(const uint4*)&L[r * 72 + c0 + 8];
    u16* d = dst + (size_t)(n0 + r) * 1024 + k0 + c0;
    *(uint4*)d = o0;
    *(uint4*)(d + 8) = o1;
}

// ---- GEMM1 (R6-proven): QKV = X @ WtA^T + b. 256x192, BK=64, 8 waves,
// dbuf-2, 4-phase, 256 blocks = 1/CU, counted vmcnt(4), rule-#21 swizzle ----
#define STA6(s, Tn) gll16(Asrc + (size_t)(s) * 64 * 1024 + ((Tn) & 15) * 64, \
                          &As[(Tn) & 1][(((s) * 64) + wave * 8) * 64])
#define STB6(s, Tn) gll16(Bsrc + (size_t)(s) * 64 * 1024 + ((Tn) & 15) * 64, \
                          &Bs[(Tn) & 1][(((s) * 64) + wave * 8) * 64])

__global__ __launch_bounds__(512, 2) void k_gemm1(
    const u16* __restrict__ Xraw, const u16* __restrict__ Xb,
    const u16* __restrict__ Bt, const void* __restrict__ bias,
    u16* __restrict__ C) {
    const int K = 1024;
    __shared__ u16 As[2][256 * 64];   // 64 KiB
    __shared__ u16 Bs[2][192 * 64];   // 48 KiB
    int f = sniff_bf16(Xraw);
    const u16* A = f ? Xraw : Xb;
    int t = threadIdx.x, wave = t >> 6, lane = t & 63;
    int bid = blockIdx.x;
    int swz = (bid & 7) * 32 + (bid >> 3);
    int bx = swz & 15, by = swz >> 4;
    int m0 = by * 256, n0 = bx * 192;
    int wr = wave >> 2, wc = wave & 3;
    int lm = lane & 15, q4 = lane >> 4;
    int l8 = lane >> 3, l7 = lane & 7;
    int scol = (l7 ^ l8) * 8;
    const u16* Asrc = A  + (size_t)(m0 + wave * 8 + l8) * K + scol;
    const u16* Bsrc = Bt + (size_t)(n0 + wave * 8 + l8) * K + scol;
    int kc0 = (q4 ^ (lm & 7)) * 8;
    int kc1 = ((4 + q4) ^ (lm & 7)) * 8;

    f32x4 acc[8][3];
    f32x4 z = {0.f, 0.f, 0.f, 0.f};
#pragma unroll
    for (int mi = 0; mi < 8; ++mi)
#pragma unroll
        for (int ni = 0; ni < 3; ++ni) acc[mi][ni] = z;

    STA6(0, 0); STA6(1, 0); STA6(2, 0); STA6(3, 0);
    STB6(0, 0); STB6(1, 0); STB6(2, 0);
    STA6(0, 1); STA6(1, 1); STA6(2, 1); STA6(3, 1);

    s16x8 afr[8][2], bfr[3][2];

    for (int T = 0; T < 16; ++T) {
        int p = T & 1;
        asm volatile("s_waitcnt vmcnt(4)\n\ts_barrier" ::: "memory");
        // ph0
#pragma unroll
        for (int mi = 0; mi < 4; ++mi) {
            int rb = (wr * 128 + mi * 16 + lm) * 64;
            afr[mi][0] = *(const s16x8*)&As[p][rb + kc0];
            afr[mi][1] = *(const s16x8*)&As[p][rb + kc1];
        }
#pragma unroll
        for (int ni = 0; ni < 2; ++ni) {
            int rb = (wc * 48 + ni * 16 + lm) * 64;
            bfr[ni][0] = *(const s16x8*)&Bs[p][rb + kc0];
            bfr[ni][1] = *(const s16x8*)&Bs[p][rb + kc1];
        }
        STB6(0, T + 1);
        __builtin_amdgcn_s_setprio(1);
#pragma unroll
        for (int mi = 0; mi < 4; ++mi)
#pragma unroll
            for (int ni = 0; ni < 2; ++ni) {
                acc[mi][ni] = __builtin_amdgcn_mfma_f32_16x16x32_bf16(
                    afr[mi][0], bfr[ni][0], acc[mi][ni], 0, 0, 0);
                acc[mi][ni] = __builtin_amdgcn_mfma_f32_16x16x32_bf16(
                    afr[mi][1], bfr[ni][1], acc[mi][ni], 0, 0, 0);
            }
        __builtin_amdgcn_s_setprio(0);
        asm volatile("s_barrier" ::: "memory");
        // ph1
#pragma unroll
        for (int mi = 4; mi < 8; ++mi) {
            int rb = (wr * 128 + mi * 16 + lm) * 64;
            afr[mi][0] = *(const s16x8*)&As[p][rb + kc0];
            afr[mi][1] = *(const s16x8*)&As[p][rb + kc1];
        }
        {
            int rb = (wc * 48 + 32 + lm) * 64;
            bfr[2][0] = *(const s16x8*)&Bs[p][rb + kc0];
            bfr[2][1] = *(const s16x8*)&Bs[p][rb + kc1];
        }
        STB6(1, T + 1); STB6(2, T + 1);
        __builtin_amdgcn_s_setprio(1);
#pragma unroll
        for (int mi = 4; mi < 8; ++mi) {
            acc[mi][2] = __builtin_amdgcn_mfma_f32_16x16x32_bf16(
                afr[mi][0], bfr[2][0], acc[mi][2], 0, 0, 0);
            acc[mi][2] = __builtin_amdgcn_mfma_f32_16x16x32_bf16(
                afr[mi][1], bfr[2][1], acc[mi][2], 0, 0, 0);
        }
        __builtin_amdgcn_s_setprio(0);
        asm volatile("s_barrier" ::: "memory");
        // ph2
        STA6(0, T + 2); STA6(1, T + 2);
        __builtin_amdgcn_s_setprio(1);
#pragma unroll
        for (int mi = 0; mi < 4; ++mi) {
            acc[mi][2] = __builtin_amdgcn_mfma_f32_16x16x32_bf16(
                afr[mi][0], bfr[2][0], acc[mi][2], 0, 0, 0);
            acc[mi][2] = __builtin_amdgcn_mfma_f32_16x16x32_bf16(
                afr[mi][1], bfr[2][1], acc[mi][2], 0, 0, 0);
        }
        __builtin_amdgcn_s_setprio(0);
        asm volatile("s_barrier" ::: "memory");
        // ph3
        STA6(2, T + 2); STA6(3, T + 2);
        __builtin_amdgcn_s_setprio(1);
#pragma unroll
        for (int mi = 4; mi < 8; ++mi)
#pragma unroll
            for (int ni = 0; ni < 2; ++ni) {
                acc[mi][ni] = __builtin_amdgcn_mfma_f32_16x16x32_bf16(
                    afr[mi][0], bfr[ni][0], acc[mi][ni], 0, 0, 0);
                acc[mi][ni] = __builtin_amdgcn_mfma_f32_16x16x32_bf16(
                    afr[mi][1], bfr[ni][1], acc[mi][ni], 0, 0, 0);
            }
        __builtin_amdgcn_s_setprio(0);
        asm volatile("s_barrier" ::: "memory");
    }
    asm volatile("s_waitcnt vmcnt(0)" ::: "memory");

    int cn = lm, cr = q4 * 4;
    float bb[3]; int hm_[3], d_[3];
#pragma unroll
    for (int ni = 0; ni < 3; ++ni) {
        int gn = n0 + wc * 48 + ni * 16 + cn;
        bb[ni] = f ? b2f(((const u16*)bias)[gn]) : ((const float*)bias)[gn];
        int kind = gn >> 10, rem = gn & 1023;
        hm_[ni] = kind * 32 + (rem >> 6);
        d_[ni] = rem & 63;
    }
#pragma unroll
    for (int mi = 0; mi < 8; ++mi)
        for (int r = 0; r < 4; ++r) {
            int gm = m0 + wr * 128 + mi * 16 + cr + r;
            int b = gm >> 11, s = gm & 2047;
#pragma unroll
            for (int ni = 0; ni < 3; ++ni) {
                size_t o = ((size_t)((hm_[ni] + b * 16) * 2048 + s)) * 64 + d_[ni];
                C[o] = f2b(acc[mi][ni][r] + bb[ni]);
            }
        }
}

// ---- GEMM2 (R7): out = AO @ WtP^T + b. 128x128, BK=64, 4 waves (64x64
// wave tile, acc[4][4]), dbuf-2, 4-phase (R6-proven hazard pattern),
// grid 256 blocks = 1/CU, LDS 64 KiB (2 blocks/CU). Ledger re-verified:
// boundary in-flight = B(T)*4 + A(T+1)*4 = 8; vmcnt(4) retires B(T),
// A(T) older/retired — never drains. A(T+2)->buf p after ph1-end barrier. ----
#define STA7(s, Tn) gll16(Asrc + (size_t)(s) * 32 * 1024 + ((Tn) & 15) * 64, \
                          &As[(Tn) & 1][(((s) * 32) + wave * 8) * 64])
#define STB7(s, Tn) gll16(Bsrc + (size_t)(s) * 32 * 1024 + ((Tn) & 15) * 64, \
                          &Bs[(Tn) & 1][(((s) * 32) + wave * 8) * 64])

__global__ __launch_bounds__(256, 2) void k_gemm2(
    const u16* __restrict__ Xraw, const u16* __restrict__ A,
    const u16* __restrict__ Bt, const void* __restrict__ bias,
    u16* __restrict__ Cb, float* __restrict__ Cf) {
    const int K = 1024, N = 1024;
    __shared__ u16 As[2][128 * 64];   // 32 KiB
    __shared__ u16 Bs[2][128 * 64];   // 32 KiB
    int f = sniff_bf16(Xraw);
    int t = threadIdx.x, wave = t >> 6, lane = t & 63;
    int bid = blockIdx.x;
    int swz = (bid & 7) * 32 + (bid >> 3);   // 256 blocks, bijective
    int bx = swz & 7, by = swz >> 3;         // 8 N-blocks x 32 M-blocks
    int m0 = by * 128, n0 = bx * 128;
    int wm = (wave >> 1) * 64, wn = (wave & 1) * 64;
    int lm = lane & 15, q4 = lane >> 4;
    int l8 = lane >> 3, l7 = lane & 7;
    int scol = (l7 ^ l8) * 8;
    const u16* Asrc = A  + (size_t)(m0 + wave * 8 + l8) * K + scol;
    const u16* Bsrc = Bt + (size_t)(n0 + wave * 8 + l8) * K + scol;
    int kc0 = (q4 ^ (lm & 7)) * 8;
    int kc1 = ((4 + q4) ^ (lm & 7)) * 8;

    f32x4 acc[4][4];
    f32x4 z = {0.f, 0.f, 0.f, 0.f};
#pragma unroll
    for (int mi = 0; mi < 4; ++mi)
#pragma unroll
        for (int ni = 0; ni < 4; ++ni) acc[mi][ni] = z;

    // prologue: A(0) 4, B(0) 4, A(1) 4 -> 12 in flight
    STA7(0, 0); STA7(1, 0); STA7(2, 0); STA7(3, 0);
    STB7(0, 0); STB7(1, 0); STB7(2, 0); STB7(3, 0);
    STA7(0, 1); STA7(1, 1); STA7(2, 1); STA7(3, 1);

    s16x8 afr[4][2], bfr[4][2];

    for (int T = 0; T < 16; ++T) {
        int p = T & 1;
        asm volatile("s_waitcnt vmcnt(4)\n\ts_barrier" ::: "memory");
        // ph0: read af[0:2], bf[0:2]; stage B.s0,s1(T+1); MFMA (0-1)x(0-1)
#pragma unroll
        for (int mi = 0; mi < 2; ++mi) {
            int rb = (wm + mi * 16 + lm) * 64;
            afr[mi][0] = *(const s16x8*)&As[p][rb + kc0];
            afr[mi][1] = *(const s16x8*)&As[p][rb + kc1];
        }
#pragma unroll
        for (int ni = 0; ni < 2; ++ni) {
            int rb = (wn + ni * 16 + lm) * 64;
            bfr[ni][0] = *(const s16x8*)&Bs[p][rb + kc0];
            bfr[ni][1] = *(const s16x8*)&Bs[p][rb + kc1];
        }
        STB7(0, T + 1); STB7(1, T + 1);
        __builtin_amdgcn_s_setprio(1);
#pragma unroll
        for (int mi = 0; mi < 2; ++mi)
#pragma unroll
            for (int ni = 0; ni < 2; ++ni) {
                acc[mi][ni] = __builtin_amdgcn_mfma_f32_16x16x32_bf16(
                    afr[mi][0], bfr[ni][0], acc[mi][ni], 0, 0, 0);
                acc[mi][ni] = __builtin_amdgcn_mfma_f32_16x16x32_bf16(
                    afr[mi][1], bfr[ni][1], acc[mi][ni], 0, 0, 0);
            }
        __builtin_amdgcn_s_setprio(0);
        asm volatile("s_barrier" ::: "memory");
        // ph1: read af[2:4], bf[2:4]; stage B.s2,s3(T+1); MFMA (2-3)x(2-3)
#pragma unroll
        for (int mi = 2; mi < 4; ++mi) {
            int rb = (wm + mi * 16 + lm) * 64;
            afr[mi][0] = *(const s16x8*)&As[p][rb + kc0];
            afr[mi][1] = *(const s16x8*)&As[p][rb + kc1];
        }
#pragma unroll
        for (int ni = 2; ni < 4; ++ni) {
            int rb = (wn + ni * 16 + lm) * 64;
            bfr[ni][0] = *(const s16x8*)&Bs[p][rb + kc0];
            bfr[ni][1] = *(const s16x8*)&Bs[p][rb + kc1];
        }
        STB7(2, T + 1); STB7(3, T + 1);
        __builtin_amdgcn_s_setprio(1);
#pragma unroll
        for (int mi = 2; mi < 4; ++mi)
#pragma unroll
            for (int ni = 2; ni < 4; ++ni) {
                acc[mi][ni] = __builtin_amdgcn_mfma_f32_16x16x32_bf16(
                    afr[mi][0], bfr[ni][0], acc[mi][ni], 0, 0, 0);
                acc[mi][ni] = __builtin_amdgcn_mfma_f32_16x16x32_bf16(
                    afr[mi][1], bfr[ni][1], acc[mi][ni], 0, 0, 0);
            }
        __builtin_amdgcn_s_setprio(0);
        asm volatile("s_barrier" ::: "memory");
        // ph2: stage A.s0,s1(T+2); MFMA (0-1)x(2-3)
        STA7(0, T + 2); STA7(1, T + 2);
        __builtin_amdgcn_s_setprio(1);
#pragma unroll
        for (int mi = 0; mi < 2; ++mi)
#pragma unroll
            for (int ni = 2; ni < 4; ++ni) {
                acc[mi][ni] = __builtin_amdgcn_mfma_f32_16x16x32_bf16(
                    afr[mi][0], bfr[ni][0], acc[mi][ni], 0, 0, 0);
                acc[mi][ni] = __builtin_amdgcn_mfma_f32_16x16x32_bf16(
                    afr[mi][1], bfr[ni][1], acc[mi][ni], 0, 0, 0);
            }
        __builtin_amdgcn_s_setprio(0);
        asm volatile("s_barrier" ::: "memory");
        // ph3: stage A.s2,s3(T+2); MFMA (2-3)x(0-1)
        STA7(2, T + 2); STA7(3, T + 2);
        __builtin_amdgcn_s_setprio(1);
#pragma unroll
        for (int mi = 2; mi < 4; ++mi)
#pragma unroll
            for (int ni = 0; ni < 2; ++ni) {
                acc[mi][ni] = __builtin_amdgcn_mfma_f32_16x16x32_bf16(
                    afr[mi][0], bfr[ni][0], acc[mi][ni], 0, 0, 0);
                acc[mi][ni] = __builtin_amdgcn_mfma_f32_16x16x32_bf16(
                    afr[mi][1], bfr[ni][1], acc[mi][ni], 0, 0, 0);
            }
        __builtin_amdgcn_s_setprio(0);
        asm volatile("s_barrier" ::: "memory");
    }
    asm volatile("s_waitcnt vmcnt(0)" ::: "memory");

    int store_f32 = (f == 0);
    int cn = lane & 15, cr = (lane >> 4) * 4;
#pragma unroll
    for (int ni = 0; ni < 4; ++ni) {
        int gn = n0 + wn + ni * 16 + cn;
        float bb = f ? b2f(((const u16*)bias)[gn]) : ((const float*)bias)[gn];
#pragma unroll
        for (int mi = 0; mi < 4; ++mi)
            for (int r = 0; r < 4; ++r) {
                int gm = m0 + wm + mi * 16 + cr + r;
                float v = acc[mi][ni][r] + bb;
                size_t o = (size_t)gm * N + gn;
                if (store_f32) Cf[o] = v;
                else           Cb[o] = f2b(v);
            }
    }
}

// ---- MFMA sparse attention (R3 structure + R7 Q-direct-to-reg:
// each wave reads only its own 16 Q-rows -> two 16B global loads at
// kernel start (latency hidden under K/V staging); Qs LDS removed,
// smem 78->69 KiB; Ps now aliases Ks region) ----
#define VP 264
#define PP 264
__global__ __launch_bounds__(256) void k_attn4(const u16* __restrict__ QKV,
                                               u16* __restrict__ AO) {
    int bx = blockIdx.x, h = blockIdx.y, b = blockIdx.z;
    int qb = bx >> 1, sb = bx & 1;
    int t = threadIdx.x, lane = t & 63, wave = t >> 6;
    int lm = lane & 15, q4 = lane >> 4;
    int nstr = qb << 3;
    int nk = nstr + (sb << 6) + 64;     // <= 248
    int r0 = (qb << 7) + (sb << 6);

    __shared__ char smem[70656];
    u16* Vts = (u16*)smem;                       // 64 x 264
    u16* Ks  = (u16*)(smem + 33792);             // 256 x 72
    u16* Ps  = (u16*)(smem + 33792);             // aliases Ks

    int hm = b * 16 + h;
    const u16* qp = QKV + ((size_t)hm * 2048 + r0) * 64;
    const u16* kp = QKV + ((size_t)(32 + hm) * 2048) * 64;
    const u16* vp = QKV + ((size_t)(64 + hm) * 2048) * 64;

    // Q direct to regs: wave's rows wave*16+lm, col groups q4*8 and q4*8+32
    const u16* qrow = qp + (wave * 16 + lm) * 64 + q4 * 8;
    s16x8 af0 = *(const s16x8*)qrow;
    s16x8 af1 = *(const s16x8*)(qrow + 32);

    uint4 zz = {0u, 0u, 0u, 0u};
    for (int c = t; c < 2048; c += 256) {
        int i = c >> 3, d0 = (c & 7) << 3;
        uint4 kv = zz;
        if (i < nk) {
            int key = (i < nstr) ? (((i >> 3) << 7) + 120 + (i & 7))
                                 : ((qb << 7) + (i - nstr));
            kv = *(const uint4*)(kp + key * 64 + d0);
        }
        *(uint4*)&Ks[i * 72 + d0] = kv;
    }
    {
        int i0 = (t & 31) * 8, d0 = (t >> 5) * 8;
        u16 m8[8][8];
        for (int r = 0; r < 8; ++r) {
            int i = i0 + r;
            uint4 vv = zz;
            if (i < nk) {
                int key = (i < nstr) ? (((i >> 3) << 7) + 120 + (i & 7))
                                     : ((qb << 7) + (i - nstr));
                vv = *(const uint4*)(vp + key * 64 + d0);
            }
            *(uint4*)m8[r] = vv;
        }
        for (int j = 0; j < 8; ++j) {
            u16 o[8];
            for (int r = 0; r < 8; ++r) o[r] = m8[r][j];
            *(uint4*)&Vts[(d0 + j) * VP + i0] = *(uint4*)o;
        }
    }
    __syncthreads();

    f32x4 acc[16];
    f32x4 z4 = {0.f, 0.f, 0.f, 0.f};
    for (int ni = 0; ni < 16; ++ni) acc[ni] = z4;
    for (int ni = 0; ni < 16; ++ni) {
        s16x8 bf0 = *(const s16x8*)&Ks[(ni * 16 + lm) * 72 + q4 * 8];
        s16x8 bf1 = *(const s16x8*)&Ks[(ni * 16 + lm) * 72 + 32 + q4 * 8];
        acc[ni] = __builtin_amdgcn_mfma_f32_16x16x32_bf16(af0, bf0, acc[ni], 0, 0, 0);
        acc[ni] = __builtin_amdgcn_mfma_f32_16x16x32_bf16(af1, bf1, acc[ni], 0, 0, 0);
    }
    __syncthreads();

    float mx[4] = {-3e38f, -3e38f, -3e38f, -3e38f};
    for (int ni = 0; ni < 16; ++ni) {
        int i = ni * 16 + lm;
        for (int reg = 0; reg < 4; ++reg) {
            int rl = (sb << 6) + wave * 16 + q4 * 4 + reg;
            bool valid = (i < nstr) || ((i - nstr) <= rl);
            float v = valid ? acc[ni][reg] * 0.125f : -3e38f;
            acc[ni][reg] = v;
            mx[reg] = fmaxf(mx[reg], v);
        }
    }
    for (int reg = 0; reg < 4; ++reg)
        for (int off = 1; off < 16; off <<= 1)
            mx[reg] = fmaxf(mx[reg], __shfl_xor(mx[reg], off, 64));
    float sm[4] = {0.f, 0.f, 0.f, 0.f};
    for (int ni = 0; ni < 16; ++ni)
        for (int reg = 0; reg < 4; ++reg) {
            float e = __expf(acc[ni][reg] - mx[reg]);
            acc[ni][reg] = e;
            sm[reg] += e;
        }
    for (int reg = 0; reg < 4; ++reg)
        for (int off = 1; off < 16; off <<= 1)
            sm[reg] += __shfl_xor(sm[reg], off, 64);
    float inv[4];
    for (int reg = 0; reg < 4; ++reg) inv[reg] = 1.f / sm[reg];

    for (int ni = 0; ni < 16; ++ni) {
        int i = ni * 16 + lm;
        for (int reg = 0; reg < 4; ++reg)
            Ps[(wave * 16 + q4 * 4 + reg) * PP + i] = f2b(acc[ni][reg]);
    }
    __syncthreads();

    f32x4 acc2[4];
    for (int ni2 = 0; ni2 < 4; ++ni2) acc2[ni2] = z4;
    for (int k0 = 0; k0 < 256; k0 += 32) {
        s16x8 pf = *(const s16x8*)&Ps[(wave * 16 + lm) * PP + k0 + q4 * 8];
        for (int ni2 = 0; ni2 < 4; ++ni2) {
            s16x8 vf = *(const s16x8*)&Vts[(ni2 * 16 + lm) * VP + k0 + q4 * 8];
            acc2[ni2] = __builtin_amdgcn_mfma_f32_16x16x32_bf16(pf, vf, acc2[ni2], 0, 0, 0);
        }
    }
    int srow = r0 + wave * 16 + q4 * 4;
    for (int ni2 = 0; ni2 < 4; ++ni2)
        for (int reg = 0; reg < 4; ++reg) {
            size_t o = ((size_t)(b * SDIM + srow + reg)) * EDIM + h * 64 + ni2 * 16 + lm;
            AO[o] = f2b(acc2[ni2][reg] * inv[reg]);
        }
}

extern "C" void kernel_launch(void* const* d_in, const int* in_sizes, int n_in,
                              void* d_out, int out_size, void* d_ws, size_t ws_size,
                              hipStream_t stream) {
    const void* X  = d_in[0];
    const void* Wa = d_in[1];
    const void* ba = d_in[2];
    const void* Wp = d_in[3];
    const void* bp = d_in[4];

    char* w = (char*)d_ws;
    u16* Xb   = (u16*)(w);
    u16* WtA  = (u16*)(w + 8388608);
    u16* WtP  = (u16*)(w + 14680064);
    u16* QKVh = (u16*)(w + 16777216);
    u16* AO   = (u16*)(w + 41943040);

    k_prep<<<dim3(48, 16, 3), 256, 0, stream>>>(X, Wa, Wp, Xb, WtA, WtP);
    k_gemm1<<<dim3(256), 512, 0, stream>>>((const u16*)X, Xb, WtA, ba, QKVh);
    k_attn4<<<dim3(32, 16, 2), 256, 0, stream>>>(QKVh, AO);
    k_gemm2<<<dim3(256), 256, 0, stream>>>((const u16*)X, AO, WtP, bp,
                                           (u16*)d_out, (float*)d_out);
}

// Round 9
// 154.336 us; speedup vs baseline: 1.0397x; 1.0397x over previous
//
#include <hip/hip_runtime.h>
#include <hip/hip_bf16.h>
#include <stdint.h>

typedef unsigned short u16;
typedef uint32_t u32;
typedef short s16x8 __attribute__((ext_vector_type(8)));
typedef float f32x4 __attribute__((ext_vector_type(4)));

#define SDIM 2048
#define EDIM 1024

static __device__ __forceinline__ float b2f(u16 v) {
    union { float f; u32 u; } c; c.u = ((u32)v) << 16; return c.f;
}
static __device__ __forceinline__ u16 f2b(float f) {
    union { float f; u32 u; } c; c.f = f;
    u32 u = c.u;
    u32 r = (u + 0x7FFFu + ((u >> 16) & 1u)) >> 16;
    return (u16)r;
}
static __device__ __forceinline__ void gll16(const u16* g, u16* l) {
    __builtin_amdgcn_global_load_lds(
        (const __attribute__((address_space(1))) void*)g,
        (__attribute__((address_space(3))) void*)l, 16, 0, 0);
}

// per-wave dtype sniff (verified R1/R5)
static __device__ __forceinline__ int sniff_bf16(const u16* __restrict__ x) {
    u16 v = x[(threadIdx.x & 63) * 2];
    int e = (v >> 7) & 0xFF;
    unsigned long long m = __ballot(e >= 90 && e <= 144);
    return __popcll(m) >= 48;
}

// ---- fused prep: z=0 Wa^T, z=1 Wp^T (LDS-tiled), z=2 X convert (fp32 path) ----
__global__ __launch_bounds__(256) void k_prep(
    const void* __restrict__ X, const void* __restrict__ Wa,
    const void* __restrict__ Wp, u16* __restrict__ Xb,
    u16* __restrict__ WtA, u16* __restrict__ WtP) {
    int f = sniff_bf16((const u16*)X);
    int z = blockIdx.z;
    int t = threadIdx.x;
    if (z == 2) {
        if (f) return;
        const float* s = (const float*)X;
        int bid = blockIdx.y * 48 + blockIdx.x;
        for (int c = bid; c < 2048; c += 768) {
            long i = ((long)c * 256 + t) * 8;
            u16 o[8];
            for (int j = 0; j < 8; ++j) o[j] = f2b(s[i + j]);
            *(uint4*)&Xb[i] = *(uint4*)o;
        }
        return;
    }
    if (z == 1 && blockIdx.x >= 16) return;
    const void* src = z ? Wp : Wa;
    u16* dst = z ? WtP : WtA;
    int Nsrc = z ? 1024 : 3072;
    int n0 = blockIdx.x * 64, k0 = blockIdx.y * 64;
    __shared__ u16 L[64 * 72];
    int r = t >> 2, c0 = (t & 3) * 16;
    u16 val[16];
    if (f) {
        const u16* s = (const u16*)src + (size_t)(k0 + r) * Nsrc + n0 + c0;
        *(uint4*)&val[0] = *(const uint4*)s;
        *(uint4*)&val[8] = *(const uint4*)(s + 8);
    } else {
        const float* s = (const float*)src + (size_t)(k0 + r) * Nsrc + n0 + c0;
        for (int j = 0; j < 16; ++j) val[j] = f2b(s[j]);
    }
    for (int j = 0; j < 16; ++j) L[(c0 + j) * 72 + r] = val[j];
    __syncthreads();
    uint4 o0 = *(const uint4*)&L[r * 72 + c0];
    uint4 o1 = *(const uint4*)&L[r * 72 + c0 + 8];
    u16* d = dst + (size_t)(n0 + r) * 1024 + k0 + c0;
    *(uint4*)d = o0;
    *(uint4*)(d + 8) = o1;
}

// ---- GEMM1 (R6-proven loop + R9 LDS-bounce epilogue): QKV = X @ WtA^T + b.
// 256x192, BK=64, 8 waves, dbuf-2, 4-phase, 256 blocks = 1/CU, counted
// vmcnt(4), rule-#21 swizzle. NEW: epilogue stages the 256x192 tile into
// the dead LDS as 3 head-slabs [256][72] (pitch 72 = 16B-aligned, banks
// rotate 4/row), then writes fully-coalesced 128B lines (WRITE_SIZE
// measured 57 MB vs 25 ideal from 32B partial-line scatter — this is the
// fix). vmcnt(0)+barrier before repurposing LDS (cross-wave gll drain). ----
#define ASL(p) (SH + (p) * 16384)
#define BSL(p) (SH + 32768 + (p) * 12288)
#define STA6(s, Tn) gll16(Asrc + (size_t)(s) * 64 * 1024 + ((Tn) & 15) * 64, \
                          &ASL((Tn) & 1)[(((s) * 64) + wave * 8) * 64])
#define STB6(s, Tn) gll16(Bsrc + (size_t)(s) * 64 * 1024 + ((Tn) & 15) * 64, \
                          &BSL((Tn) & 1)[(((s) * 64) + wave * 8) * 64])

__global__ __launch_bounds__(512, 2) void k_gemm1(
    const u16* __restrict__ Xraw, const u16* __restrict__ Xb,
    const u16* __restrict__ Bt, const void* __restrict__ bias,
    u16* __restrict__ C) {
    const int K = 1024;
    __shared__ u16 SH[57344];   // 112 KiB: A dbuf 2x16384, B dbuf 2x12288
    int f = sniff_bf16(Xraw);
    const u16* A = f ? Xraw : Xb;
    int t = threadIdx.x, wave = t >> 6, lane = t & 63;
    int bid = blockIdx.x;
    int swz = (bid & 7) * 32 + (bid >> 3);
    int bx = swz & 15, by = swz >> 4;
    int m0 = by * 256, n0 = bx * 192;
    int wr = wave >> 2, wc = wave & 3;
    int lm = lane & 15, q4 = lane >> 4;
    int l8 = lane >> 3, l7 = lane & 7;
    int scol = (l7 ^ l8) * 8;
    const u16* Asrc = A  + (size_t)(m0 + wave * 8 + l8) * K + scol;
    const u16* Bsrc = Bt + (size_t)(n0 + wave * 8 + l8) * K + scol;
    int kc0 = (q4 ^ (lm & 7)) * 8;
    int kc1 = ((4 + q4) ^ (lm & 7)) * 8;

    f32x4 acc[8][3];
    f32x4 z = {0.f, 0.f, 0.f, 0.f};
#pragma unroll
    for (int mi = 0; mi < 8; ++mi)
#pragma unroll
        for (int ni = 0; ni < 3; ++ni) acc[mi][ni] = z;

    STA6(0, 0); STA6(1, 0); STA6(2, 0); STA6(3, 0);
    STB6(0, 0); STB6(1, 0); STB6(2, 0);
    STA6(0, 1); STA6(1, 1); STA6(2, 1); STA6(3, 1);

    s16x8 afr[8][2], bfr[3][2];

    for (int T = 0; T < 16; ++T) {
        int p = T & 1;
        asm volatile("s_waitcnt vmcnt(4)\n\ts_barrier" ::: "memory");
        // ph0
#pragma unroll
        for (int mi = 0; mi < 4; ++mi) {
            int rb = (wr * 128 + mi * 16 + lm) * 64;
            afr[mi][0] = *(const s16x8*)&ASL(p)[rb + kc0];
            afr[mi][1] = *(const s16x8*)&ASL(p)[rb + kc1];
        }
#pragma unroll
        for (int ni = 0; ni < 2; ++ni) {
            int rb = (wc * 48 + ni * 16 + lm) * 64;
            bfr[ni][0] = *(const s16x8*)&BSL(p)[rb + kc0];
            bfr[ni][1] = *(const s16x8*)&BSL(p)[rb + kc1];
        }
        STB6(0, T + 1);
        __builtin_amdgcn_s_setprio(1);
#pragma unroll
        for (int mi = 0; mi < 4; ++mi)
#pragma unroll
            for (int ni = 0; ni < 2; ++ni) {
                acc[mi][ni] = __builtin_amdgcn_mfma_f32_16x16x32_bf16(
                    afr[mi][0], bfr[ni][0], acc[mi][ni], 0, 0, 0);
                acc[mi][ni] = __builtin_amdgcn_mfma_f32_16x16x32_bf16(
                    afr[mi][1], bfr[ni][1], acc[mi][ni], 0, 0, 0);
            }
        __builtin_amdgcn_s_setprio(0);
        asm volatile("s_barrier" ::: "memory");
        // ph1
#pragma unroll
        for (int mi = 4; mi < 8; ++mi) {
            int rb = (wr * 128 + mi * 16 + lm) * 64;
            afr[mi][0] = *(const s16x8*)&ASL(p)[rb + kc0];
            afr[mi][1] = *(const s16x8*)&ASL(p)[rb + kc1];
        }
        {
            int rb = (wc * 48 + 32 + lm) * 64;
            bfr[2][0] = *(const s16x8*)&BSL(p)[rb + kc0];
            bfr[2][1] = *(const s16x8*)&BSL(p)[rb + kc1];
        }
        STB6(1, T + 1); STB6(2, T + 1);
        __builtin_amdgcn_s_setprio(1);
#pragma unroll
        for (int mi = 4; mi < 8; ++mi) {
            acc[mi][2] = __builtin_amdgcn_mfma_f32_16x16x32_bf16(
                afr[mi][0], bfr[2][0], acc[mi][2], 0, 0, 0);
            acc[mi][2] = __builtin_amdgcn_mfma_f32_16x16x32_bf16(
                afr[mi][1], bfr[2][1], acc[mi][2], 0, 0, 0);
        }
        __builtin_amdgcn_s_setprio(0);
        asm volatile("s_barrier" ::: "memory");
        // ph2
        STA6(0, T + 2); STA6(1, T + 2);
        __builtin_amdgcn_s_setprio(1);
#pragma unroll
        for (int mi = 0; mi < 4; ++mi) {
            acc[mi][2] = __builtin_amdgcn_mfma_f32_16x16x32_bf16(
                afr[mi][0], bfr[2][0], acc[mi][2], 0, 0, 0);
            acc[mi][2] = __builtin_amdgcn_mfma_f32_16x16x32_bf16(
                afr[mi][1], bfr[2][1], acc[mi][2], 0, 0, 0);
        }
        __builtin_amdgcn_s_setprio(0);
        asm volatile("s_barrier" ::: "memory");
        // ph3
        STA6(2, T + 2); STA6(3, T + 2);
        __builtin_amdgcn_s_setprio(1);
#pragma unroll
        for (int mi = 4; mi < 8; ++mi)
#pragma unroll
            for (int ni = 0; ni < 2; ++ni) {
                acc[mi][ni] = __builtin_amdgcn_mfma_f32_16x16x32_bf16(
                    afr[mi][0], bfr[ni][0], acc[mi][ni], 0, 0, 0);
                acc[mi][ni] = __builtin_amdgcn_mfma_f32_16x16x32_bf16(
                    afr[mi][1], bfr[ni][1], acc[mi][ni], 0, 0, 0);
            }
        __builtin_amdgcn_s_setprio(0);
        asm volatile("s_barrier" ::: "memory");
    }
    asm volatile("s_waitcnt vmcnt(0)" ::: "memory");
    __syncthreads();   // all waves' trailing gll-writes drained before LDS repurpose

    // ---- R9 bounce epilogue ----
    float bb[3];
#pragma unroll
    for (int ni = 0; ni < 3; ++ni) {
        int gn = n0 + wc * 48 + ni * 16 + lm;
        bb[ni] = f ? b2f(((const u16*)bias)[gn]) : ((const float*)bias)[gn];
    }
    // stage into 3 slabs [256][72]
#pragma unroll
    for (int mi = 0; mi < 8; ++mi)
        for (int r = 0; r < 4; ++r) {
            int row = wr * 128 + mi * 16 + q4 * 4 + r;
#pragma unroll
            for (int ni = 0; ni < 3; ++ni) {
                int ld = wc * 48 + ni * 16 + lm;
                int sl = ld >> 6, d = ld & 63;
                SH[sl * 18432 + row * 72 + d] = f2b(acc[mi][ni][r] + bb[ni]);
            }
        }
    __syncthreads();
    int bB = m0 >> 11, ms = m0 & 2047;
#pragma unroll
    for (int sl = 0; sl < 3; ++sl) {
        int gnb = n0 + sl * 64;
        int kind = gnb >> 10, rem = gnb & 1023;
        int hmh = kind * 32 + (rem >> 6);
        size_t base = ((size_t)(hmh + bB * 16)) * 2048 * 64;
#pragma unroll
        for (int i = 0; i < 4; ++i) {
            int c = t + i * 512;
            int s_ = c >> 3, d0 = (c & 7) * 8;
            uint4 v = *(const uint4*)&SH[sl * 18432 + s_ * 72 + d0];
            *(uint4*)&C[base + (size_t)(ms + s_) * 64 + d0] = v;
        }
    }
}

// ---- GEMM2 (R6-proven revert): out = AO @ WtP^T + b. 64x128, BK=32,
// triple-buffer counted vmcnt + T2 XOR-swizzle. (R7's 4-phase port
// regressed: 128 barriers/block at 4 MFMA/barrier — reverted.) ----
__global__ __launch_bounds__(256) void k_gemm2(
    const u16* __restrict__ Xraw, const u16* __restrict__ A,
    const u16* __restrict__ Bt, const void* __restrict__ bias,
    u16* __restrict__ Cb, float* __restrict__ Cf) {
    const int K = 1024, N = 1024;
    __shared__ u16 As[3][2048];
    __shared__ u16 Bs[3][4096];
    int f = sniff_bf16(Xraw);
    int t = threadIdx.x, wave = t >> 6, lane = t & 63;
    int m0 = blockIdx.y * 64, n0 = blockIdx.x * 128;
    int wm = (wave >> 1) * 32, wn = (wave & 1) * 64;
    int lm = lane & 15;
    int lk = (((lane >> 4) ^ ((lane >> 1) & 3))) * 8;
    int sr = t >> 2;
    int sc = ((t & 3) ^ ((t >> 3) & 3)) * 8;
    const u16* Ap = A + (size_t)(m0 + sr) * K + sc;
    const u16* Bp = Bt + (size_t)(n0 + sr) * K + sc;
    int wo = wave * 512;

    f32x4 acc[2][4];
    f32x4 z = {0.f, 0.f, 0.f, 0.f};
    for (int mi = 0; mi < 2; ++mi)
        for (int ni = 0; ni < 4; ++ni) acc[mi][ni] = z;

    gll16(Ap, &As[0][wo]);
    gll16(Bp, &Bs[0][wo]);
    gll16(Bp + (size_t)64 * K, &Bs[0][wo + 2048]);
    gll16(Ap + 32, &As[1][wo]);
    gll16(Bp + 32, &Bs[1][wo]);
    gll16(Bp + (size_t)64 * K + 32, &Bs[1][wo + 2048]);

    u16 *Ac = &As[0][0], *An = &As[1][0], *At = &As[2][0];
    u16 *Bc = &Bs[0][0], *Bn = &Bs[1][0], *Btg = &Bs[2][0];

    for (int it = 0; it < 32; ++it) {
        asm volatile("s_waitcnt vmcnt(3)\n\ts_barrier" ::: "memory");
        int kn = ((it + 2) & 31) * 32;
        gll16(Ap + kn, At + wo);
        gll16(Bp + kn, Btg + wo);
        gll16(Bp + (size_t)64 * K + kn, Btg + wo + 2048);

        s16x8 af[2], bfr[4];
        for (int mi = 0; mi < 2; ++mi)
            af[mi] = *(const s16x8*)&Ac[(wm + mi * 16 + lm) * 32 + lk];
        for (int ni = 0; ni < 4; ++ni)
            bfr[ni] = *(const s16x8*)&Bc[(wn + ni * 16 + lm) * 32 + lk];
        for (int mi = 0; mi < 2; ++mi)
            for (int ni = 0; ni < 4; ++ni)
                acc[mi][ni] = __builtin_amdgcn_mfma_f32_16x16x32_bf16(
                    af[mi], bfr[ni], acc[mi][ni], 0, 0, 0);

        u16* tp = Ac; Ac = An; An = At; At = tp;
        tp = Bc; Bc = Bn; Bn = Btg; Btg = tp;
    }
    asm volatile("s_waitcnt vmcnt(0)" ::: "memory");

    int store_f32 = (f == 0);
    int cn = lane & 15, cr = (lane >> 4) * 4;
    for (int ni = 0; ni < 4; ++ni) {
        int gn = n0 + wn + ni * 16 + cn;
        float bb = f ? b2f(((const u16*)bias)[gn]) : ((const float*)bias)[gn];
        for (int mi = 0; mi < 2; ++mi)
            for (int r = 0; r < 4; ++r) {
                int gm = m0 + wm + mi * 16 + cr + r;
                float v = acc[mi][ni][r] + bb;
                size_t o = (size_t)gm * N + gn;
                if (store_f32) Cf[o] = v;
                else           Cb[o] = f2b(v);
            }
    }
}

// ---- MFMA sparse attention (R6-exact revert: Qs staging, fixed bounds) ----
#define VP 264
#define PP 264
__global__ __launch_bounds__(256) void k_attn4(const u16* __restrict__ QKV,
                                               u16* __restrict__ AO) {
    int bx = blockIdx.x, h = blockIdx.y, b = blockIdx.z;
    int qb = bx >> 1, sb = bx & 1;
    int t = threadIdx.x, lane = t & 63, wave = t >> 6;
    int lm = lane & 15, q4 = lane >> 4;
    int nstr = qb << 3;
    int nk = nstr + (sb << 6) + 64;     // <= 248
    int r0 = (qb << 7) + (sb << 6);

    __shared__ char smem[79872];
    u16* Vts = (u16*)smem;                       // 64 x 264
    u16* Qs  = (u16*)(smem + 33792);             // 64 x 72
    u16* Ks  = (u16*)(smem + 33792 + 9216);      // 256 x 72
    u16* Ps  = (u16*)(smem + 33792);             // aliases Qs+Ks

    int hm = b * 16 + h;
    const u16* qp = QKV + ((size_t)hm * 2048 + r0) * 64;
    const u16* kp = QKV + ((size_t)(32 + hm) * 2048) * 64;
    const u16* vp = QKV + ((size_t)(64 + hm) * 2048) * 64;

    for (int c = t; c < 512; c += 256) {
        int r = c >> 3, d0 = (c & 7) << 3;
        *(uint4*)&Qs[r * 72 + d0] = *(const uint4*)(qp + c * 8);
    }
    uint4 zz = {0u, 0u, 0u, 0u};
    for (int c = t; c < 2048; c += 256) {
        int i = c >> 3, d0 = (c & 7) << 3;
        uint4 kv = zz;
        if (i < nk) {
            int key = (i < nstr) ? (((i >> 3) << 7) + 120 + (i & 7))
                                 : ((qb << 7) + (i - nstr));
            kv = *(const uint4*)(kp + key * 64 + d0);
        }
        *(uint4*)&Ks[i * 72 + d0] = kv;
    }
    {
        int i0 = (t & 31) * 8, d0 = (t >> 5) * 8;
        u16 m8[8][8];
        for (int r = 0; r < 8; ++r) {
            int i = i0 + r;
            uint4 vv = zz;
            if (i < nk) {
                int key = (i < nstr) ? (((i >> 3) << 7) + 120 + (i & 7))
                                     : ((qb << 7) + (i - nstr));
                vv = *(const uint4*)(vp + key * 64 + d0);
            }
            *(uint4*)m8[r] = vv;
        }
        for (int j = 0; j < 8; ++j) {
            u16 o[8];
            for (int r = 0; r < 8; ++r) o[r] = m8[r][j];
            *(uint4*)&Vts[(d0 + j) * VP + i0] = *(uint4*)o;
        }
    }
    __syncthreads();

    f32x4 acc[16];
    f32x4 z4 = {0.f, 0.f, 0.f, 0.f};
    for (int ni = 0; ni < 16; ++ni) acc[ni] = z4;
    s16x8 af0 = *(const s16x8*)&Qs[(wave * 16 + lm) * 72 + q4 * 8];
    s16x8 af1 = *(const s16x8*)&Qs[(wave * 16 + lm) * 72 + 32 + q4 * 8];
    for (int ni = 0; ni < 16; ++ni) {
        s16x8 bf0 = *(const s16x8*)&Ks[(ni * 16 + lm) * 72 + q4 * 8];
        s16x8 bf1 = *(const s16x8*)&Ks[(ni * 16 + lm) * 72 + 32 + q4 * 8];
        acc[ni] = __builtin_amdgcn_mfma_f32_16x16x32_bf16(af0, bf0, acc[ni], 0, 0, 0);
        acc[ni] = __builtin_amdgcn_mfma_f32_16x16x32_bf16(af1, bf1, acc[ni], 0, 0, 0);
    }
    __syncthreads();

    float mx[4] = {-3e38f, -3e38f, -3e38f, -3e38f};
    for (int ni = 0; ni < 16; ++ni) {
        int i = ni * 16 + lm;
        for (int reg = 0; reg < 4; ++reg) {
            int rl = (sb << 6) + wave * 16 + q4 * 4 + reg;
            bool valid = (i < nstr) || ((i - nstr) <= rl);
            float v = valid ? acc[ni][reg] * 0.125f : -3e38f;
            acc[ni][reg] = v;
            mx[reg] = fmaxf(mx[reg], v);
        }
    }
    for (int reg = 0; reg < 4; ++reg)
        for (int off = 1; off < 16; off <<= 1)
            mx[reg] = fmaxf(mx[reg], __shfl_xor(mx[reg], off, 64));
    float sm[4] = {0.f, 0.f, 0.f, 0.f};
    for (int ni = 0; ni < 16; ++ni)
        for (int reg = 0; reg < 4; ++reg) {
            float e = __expf(acc[ni][reg] - mx[reg]);
            acc[ni][reg] = e;
            sm[reg] += e;
        }
    for (int reg = 0; reg < 4; ++reg)
        for (int off = 1; off < 16; off <<= 1)
            sm[reg] += __shfl_xor(sm[reg], off, 64);
    float inv[4];
    for (int reg = 0; reg < 4; ++reg) inv[reg] = 1.f / sm[reg];

    for (int ni = 0; ni < 16; ++ni) {
        int i = ni * 16 + lm;
        for (int reg = 0; reg < 4; ++reg)
            Ps[(wave * 16 + q4 * 4 + reg) * PP + i] = f2b(acc[ni][reg]);
    }
    __syncthreads();

    f32x4 acc2[4];
    for (int ni2 = 0; ni2 < 4; ++ni2) acc2[ni2] = z4;
    for (int k0 = 0; k0 < 256; k0 += 32) {
        s16x8 pf = *(const s16x8*)&Ps[(wave * 16 + lm) * PP + k0 + q4 * 8];
        for (int ni2 = 0; ni2 < 4; ++ni2) {
            s16x8 vf = *(const s16x8*)&Vts[(ni2 * 16 + lm) * VP + k0 + q4 * 8];
            acc2[ni2] = __builtin_amdgcn_mfma_f32_16x16x32_bf16(pf, vf, acc2[ni2], 0, 0, 0);
        }
    }
    int srow = r0 + wave * 16 + q4 * 4;
    for (int ni2 = 0; ni2 < 4; ++ni2)
        for (int reg = 0; reg < 4; ++reg) {
            size_t o = ((size_t)(b * SDIM + srow + reg)) * EDIM + h * 64 + ni2 * 16 + lm;
            AO[o] = f2b(acc2[ni2][reg] * inv[reg]);
        }
}

extern "C" void kernel_launch(void* const* d_in, const int* in_sizes, int n_in,
                              void* d_out, int out_size, void* d_ws, size_t ws_size,
                              hipStream_t stream) {
    const void* X  = d_in[0];
    const void* Wa = d_in[1];
    const void* ba = d_in[2];
    const void* Wp = d_in[3];
    const void* bp = d_in[4];

    char* w = (char*)d_ws;
    u16* Xb   = (u16*)(w);
    u16* WtA  = (u16*)(w + 8388608);
    u16* WtP  = (u16*)(w + 14680064);
    u16* QKVh = (u16*)(w + 16777216);
    u16* AO   = (u16*)(w + 41943040);

    k_prep<<<dim3(48, 16, 3), 256, 0, stream>>>(X, Wa, Wp, Xb, WtA, WtP);
    k_gemm1<<<dim3(256), 512, 0, stream>>>((const u16*)X, Xb, WtA, ba, QKVh);
    k_attn4<<<dim3(32, 16, 2), 256, 0, stream>>>(QKVh, AO);
    k_gemm2<<<dim3(8, 64), 256, 0, stream>>>((const u16*)X, AO, WtP, bp,
                                             (u16*)d_out, (float*)d_out);
}

// Round 10
// 153.336 us; speedup vs baseline: 1.0464x; 1.0065x over previous
//
#include <hip/hip_runtime.h>
#include <hip/hip_bf16.h>
#include <stdint.h>

typedef unsigned short u16;
typedef uint32_t u32;
typedef short s16x8 __attribute__((ext_vector_type(8)));
typedef float f32x4 __attribute__((ext_vector_type(4)));

#define SDIM 2048
#define EDIM 1024

static __device__ __forceinline__ float b2f(u16 v) {
    union { float f; u32 u; } c; c.u = ((u32)v) << 16; return c.f;
}
static __device__ __forceinline__ u16 f2b(float f) {
    union { float f; u32 u; } c; c.f = f;
    u32 u = c.u;
    u32 r = (u + 0x7FFFu + ((u >> 16) & 1u)) >> 16;
    return (u16)r;
}
static __device__ __forceinline__ void gll16(const u16* g, u16* l) {
    __builtin_amdgcn_global_load_lds(
        (const __attribute__((address_space(1))) void*)g,
        (__attribute__((address_space(3))) void*)l, 16, 0, 0);
}

// per-wave dtype sniff (verified R1/R5)
static __device__ __forceinline__ int sniff_bf16(const u16* __restrict__ x) {
    u16 v = x[(threadIdx.x & 63) * 2];
    int e = (v >> 7) & 0xFF;
    unsigned long long m = __ballot(e >= 90 && e <= 144);
    return __popcll(m) >= 48;
}

// ---- fused prep: z=0 Wa^T, z=1 Wp^T (LDS-tiled), z=2 X convert (fp32 path) ----
__global__ __launch_bounds__(256) void k_prep(
    const void* __restrict__ X, const void* __restrict__ Wa,
    const void* __restrict__ Wp, u16* __restrict__ Xb,
    u16* __restrict__ WtA, u16* __restrict__ WtP) {
    int f = sniff_bf16((const u16*)X);
    int z = blockIdx.z;
    int t = threadIdx.x;
    if (z == 2) {
        if (f) return;
        const float* s = (const float*)X;
        int bid = blockIdx.y * 48 + blockIdx.x;
        for (int c = bid; c < 2048; c += 768) {
            long i = ((long)c * 256 + t) * 8;
            u16 o[8];
            for (int j = 0; j < 8; ++j) o[j] = f2b(s[i + j]);
            *(uint4*)&Xb[i] = *(uint4*)o;
        }
        return;
    }
    if (z == 1 && blockIdx.x >= 16) return;
    const void* src = z ? Wp : Wa;
    u16* dst = z ? WtP : WtA;
    int Nsrc = z ? 1024 : 3072;
    int n0 = blockIdx.x * 64, k0 = blockIdx.y * 64;
    __shared__ u16 L[64 * 72];
    int r = t >> 2, c0 = (t & 3) * 16;
    u16 val[16];
    if (f) {
        const u16* s = (const u16*)src + (size_t)(k0 + r) * Nsrc + n0 + c0;
        *(uint4*)&val[0] = *(const uint4*)s;
        *(uint4*)&val[8] = *(const uint4*)(s + 8);
    } else {
        const float* s = (const float*)src + (size_t)(k0 + r) * Nsrc + n0 + c0;
        for (int j = 0; j < 16; ++j) val[j] = f2b(s[j]);
    }
    for (int j = 0; j < 16; ++j) L[(c0 + j) * 72 + r] = val[j];
    __syncthreads();
    uint4 o0 = *(const uint4*)&L[r * 72 + c0];
    uint4 o1 = *(const uint4*)&L[r * 72 + c0 + 8];
    u16* d = dst + (size_t)(n0 + r) * 1024 + k0 + c0;
    *(uint4*)d = o0;
    *(uint4*)(d + 8) = o1;
}

// ---- GEMM1 (R9-proven): 256x192, BK=64, 8 waves, dbuf-2, 4-phase,
// 256 blocks = 1/CU, counted vmcnt(4), rule-#21 swizzle, LDS-bounce epilogue ----
#define ASL(p) (SH + (p) * 16384)
#define BSL(p) (SH + 32768 + (p) * 12288)
#define STA6(s, Tn) gll16(Asrc + (size_t)(s) * 64 * 1024 + ((Tn) & 15) * 64, \
                          &ASL((Tn) & 1)[(((s) * 64) + wave * 8) * 64])
#define STB6(s, Tn) gll16(Bsrc + (size_t)(s) * 64 * 1024 + ((Tn) & 15) * 64, \
                          &BSL((Tn) & 1)[(((s) * 64) + wave * 8) * 64])

__global__ __launch_bounds__(512, 2) void k_gemm1(
    const u16* __restrict__ Xraw, const u16* __restrict__ Xb,
    const u16* __restrict__ Bt, const void* __restrict__ bias,
    u16* __restrict__ C) {
    const int K = 1024;
    __shared__ u16 SH[57344];   // 112 KiB: A dbuf 2x16384, B dbuf 2x12288
    int f = sniff_bf16(Xraw);
    const u16* A = f ? Xraw : Xb;
    int t = threadIdx.x, wave = t >> 6, lane = t & 63;
    int bid = blockIdx.x;
    int swz = (bid & 7) * 32 + (bid >> 3);
    int bx = swz & 15, by = swz >> 4;
    int m0 = by * 256, n0 = bx * 192;
    int wr = wave >> 2, wc = wave & 3;
    int lm = lane & 15, q4 = lane >> 4;
    int l8 = lane >> 3, l7 = lane & 7;
    int scol = (l7 ^ l8) * 8;
    const u16* Asrc = A  + (size_t)(m0 + wave * 8 + l8) * K + scol;
    const u16* Bsrc = Bt + (size_t)(n0 + wave * 8 + l8) * K + scol;
    int kc0 = (q4 ^ (lm & 7)) * 8;
    int kc1 = ((4 + q4) ^ (lm & 7)) * 8;

    f32x4 acc[8][3];
    f32x4 z = {0.f, 0.f, 0.f, 0.f};
#pragma unroll
    for (int mi = 0; mi < 8; ++mi)
#pragma unroll
        for (int ni = 0; ni < 3; ++ni) acc[mi][ni] = z;

    STA6(0, 0); STA6(1, 0); STA6(2, 0); STA6(3, 0);
    STB6(0, 0); STB6(1, 0); STB6(2, 0);
    STA6(0, 1); STA6(1, 1); STA6(2, 1); STA6(3, 1);

    s16x8 afr[8][2], bfr[3][2];

    for (int T = 0; T < 16; ++T) {
        int p = T & 1;
        asm volatile("s_waitcnt vmcnt(4)\n\ts_barrier" ::: "memory");
        // ph0
#pragma unroll
        for (int mi = 0; mi < 4; ++mi) {
            int rb = (wr * 128 + mi * 16 + lm) * 64;
            afr[mi][0] = *(const s16x8*)&ASL(p)[rb + kc0];
            afr[mi][1] = *(const s16x8*)&ASL(p)[rb + kc1];
        }
#pragma unroll
        for (int ni = 0; ni < 2; ++ni) {
            int rb = (wc * 48 + ni * 16 + lm) * 64;
            bfr[ni][0] = *(const s16x8*)&BSL(p)[rb + kc0];
            bfr[ni][1] = *(const s16x8*)&BSL(p)[rb + kc1];
        }
        STB6(0, T + 1);
        __builtin_amdgcn_s_setprio(1);
#pragma unroll
        for (int mi = 0; mi < 4; ++mi)
#pragma unroll
            for (int ni = 0; ni < 2; ++ni) {
                acc[mi][ni] = __builtin_amdgcn_mfma_f32_16x16x32_bf16(
                    afr[mi][0], bfr[ni][0], acc[mi][ni], 0, 0, 0);
                acc[mi][ni] = __builtin_amdgcn_mfma_f32_16x16x32_bf16(
                    afr[mi][1], bfr[ni][1], acc[mi][ni], 0, 0, 0);
            }
        __builtin_amdgcn_s_setprio(0);
        asm volatile("s_barrier" ::: "memory");
        // ph1
#pragma unroll
        for (int mi = 4; mi < 8; ++mi) {
            int rb = (wr * 128 + mi * 16 + lm) * 64;
            afr[mi][0] = *(const s16x8*)&ASL(p)[rb + kc0];
            afr[mi][1] = *(const s16x8*)&ASL(p)[rb + kc1];
        }
        {
            int rb = (wc * 48 + 32 + lm) * 64;
            bfr[2][0] = *(const s16x8*)&BSL(p)[rb + kc0];
            bfr[2][1] = *(const s16x8*)&BSL(p)[rb + kc1];
        }
        STB6(1, T + 1); STB6(2, T + 1);
        __builtin_amdgcn_s_setprio(1);
#pragma unroll
        for (int mi = 4; mi < 8; ++mi) {
            acc[mi][2] = __builtin_amdgcn_mfma_f32_16x16x32_bf16(
                afr[mi][0], bfr[2][0], acc[mi][2], 0, 0, 0);
            acc[mi][2] = __builtin_amdgcn_mfma_f32_16x16x32_bf16(
                afr[mi][1], bfr[2][1], acc[mi][2], 0, 0, 0);
        }
        __builtin_amdgcn_s_setprio(0);
        asm volatile("s_barrier" ::: "memory");
        // ph2
        STA6(0, T + 2); STA6(1, T + 2);
        __builtin_amdgcn_s_setprio(1);
#pragma unroll
        for (int mi = 0; mi < 4; ++mi) {
            acc[mi][2] = __builtin_amdgcn_mfma_f32_16x16x32_bf16(
                afr[mi][0], bfr[2][0], acc[mi][2], 0, 0, 0);
            acc[mi][2] = __builtin_amdgcn_mfma_f32_16x16x32_bf16(
                afr[mi][1], bfr[2][1], acc[mi][2], 0, 0, 0);
        }
        __builtin_amdgcn_s_setprio(0);
        asm volatile("s_barrier" ::: "memory");
        // ph3
        STA6(2, T + 2); STA6(3, T + 2);
        __builtin_amdgcn_s_setprio(1);
#pragma unroll
        for (int mi = 4; mi < 8; ++mi)
#pragma unroll
            for (int ni = 0; ni < 2; ++ni) {
                acc[mi][ni] = __builtin_amdgcn_mfma_f32_16x16x32_bf16(
                    afr[mi][0], bfr[ni][0], acc[mi][ni], 0, 0, 0);
                acc[mi][ni] = __builtin_amdgcn_mfma_f32_16x16x32_bf16(
                    afr[mi][1], bfr[ni][1], acc[mi][ni], 0, 0, 0);
            }
        __builtin_amdgcn_s_setprio(0);
        asm volatile("s_barrier" ::: "memory");
    }
    asm volatile("s_waitcnt vmcnt(0)" ::: "memory");
    __syncthreads();   // all waves' trailing gll-writes drained before LDS repurpose

    // ---- R9 bounce epilogue ----
    float bb[3];
#pragma unroll
    for (int ni = 0; ni < 3; ++ni) {
        int gn = n0 + wc * 48 + ni * 16 + lm;
        bb[ni] = f ? b2f(((const u16*)bias)[gn]) : ((const float*)bias)[gn];
    }
#pragma unroll
    for (int mi = 0; mi < 8; ++mi)
        for (int r = 0; r < 4; ++r) {
            int row = wr * 128 + mi * 16 + q4 * 4 + r;
#pragma unroll
            for (int ni = 0; ni < 3; ++ni) {
                int ld = wc * 48 + ni * 16 + lm;
                int sl = ld >> 6, d = ld & 63;
                SH[sl * 18432 + row * 72 + d] = f2b(acc[mi][ni][r] + bb[ni]);
            }
        }
    __syncthreads();
    int bB = m0 >> 11, ms = m0 & 2047;
#pragma unroll
    for (int sl = 0; sl < 3; ++sl) {
        int gnb = n0 + sl * 64;
        int kind = gnb >> 10, rem = gnb & 1023;
        int hmh = kind * 32 + (rem >> 6);
        size_t base = ((size_t)(hmh + bB * 16)) * 2048 * 64;
#pragma unroll
        for (int i = 0; i < 4; ++i) {
            int c = t + i * 512;
            int s_ = c >> 3, d0 = (c & 7) * 8;
            uint4 v = *(const uint4*)&SH[sl * 18432 + s_ * 72 + d0];
            *(uint4*)&C[base + (size_t)(ms + s_) * 64 + d0] = v;
        }
    }
}

// ---- GEMM2 (R10): out = AO @ WtP^T + b. 64x128 tile, BK=64, tri-buffer
// counted vmcnt. Same R2-proven skeleton, but BK doubled: per K-tile each
// wave does 16 MFMA / 12 ds_read / 6 gll16 / ONE barrier (was 8/6/3/1 at
// BK=32) — barrier count halves (32->16), MFMA-per-barrier doubles (R8
// lesson: amortize barriers with register-only MFMA, don't add barriers).
// LDS 3 x 24 KiB = 72 KiB -> 2 blocks/CU (grid 512 = 2/CU, iso-occupancy).
// Ledger: prologue stages T0,T1 (12 in flight); at tile it wait vmcnt(6)
// retires exactly T(it)'s 6 loads (in-order); body stages T(it+2) back to
// 12 — never drains. Tail wraps &15 into dead buffers; vmcnt(0) after.
// Swizzle (rule #21): LDS[r][g]=global g^(r&7) via pre-swizzled source col
// (sg ^ (srow&7)); read col (ks*4+q4)^(lm&7) — row bases all 0 mod 8. ----
#define G2A(s, Tn, dst) gll16(Ap + (size_t)(s) * 32 * 1024 + ((Tn) & 15) * 64, \
                              (dst) + (s) * 2048 + t * 8)
#define G2B(s, Tn, dst) gll16(Bp + (size_t)(s) * 32 * 1024 + ((Tn) & 15) * 64, \
                              (dst) + (s) * 2048 + t * 8)

__global__ __launch_bounds__(256) void k_gemm2(
    const u16* __restrict__ Xraw, const u16* __restrict__ A,
    const u16* __restrict__ Bt, const void* __restrict__ bias,
    u16* __restrict__ Cb, float* __restrict__ Cf) {
    const int K = 1024, N = 1024;
    __shared__ u16 As[3][64 * 64];    // 3 x 8 KiB
    __shared__ u16 Bs[3][128 * 64];   // 3 x 16 KiB
    int f = sniff_bf16(Xraw);
    int t = threadIdx.x, wave = t >> 6, lane = t & 63;
    int m0 = blockIdx.y * 64, n0 = blockIdx.x * 128;
    int wm = (wave >> 1) * 32, wn = (wave & 1) * 64;
    int lm = lane & 15, q4 = lane >> 4;
    int srow = t >> 3, sg = t & 7;
    int scol = (sg ^ (srow & 7)) * 8;   // pre-swizzled source col (row%8 key)
    const u16* Ap = A  + (size_t)(m0 + srow) * K + scol;
    const u16* Bp = Bt + (size_t)(n0 + srow) * K + scol;
    int kc0 = (q4 ^ (lm & 7)) * 8;
    int kc1 = ((4 + q4) ^ (lm & 7)) * 8;

    f32x4 acc[2][4];
    f32x4 z = {0.f, 0.f, 0.f, 0.f};
#pragma unroll
    for (int mi = 0; mi < 2; ++mi)
#pragma unroll
        for (int ni = 0; ni < 4; ++ni) acc[mi][ni] = z;

    // prologue: T0 -> buf0, T1 -> buf1 (12 loads in flight)
    G2A(0, 0, &As[0][0]); G2A(1, 0, &As[0][0]);
    G2B(0, 0, &Bs[0][0]); G2B(1, 0, &Bs[0][0]); G2B(2, 0, &Bs[0][0]); G2B(3, 0, &Bs[0][0]);
    G2A(0, 1, &As[1][0]); G2A(1, 1, &As[1][0]);
    G2B(0, 1, &Bs[1][0]); G2B(1, 1, &Bs[1][0]); G2B(2, 1, &Bs[1][0]); G2B(3, 1, &Bs[1][0]);

    u16 *Ac = &As[0][0], *An = &As[1][0], *At = &As[2][0];
    u16 *Bc = &Bs[0][0], *Bn = &Bs[1][0], *Btg = &Bs[2][0];

    for (int it = 0; it < 16; ++it) {
        asm volatile("s_waitcnt vmcnt(6)\n\ts_barrier" ::: "memory");
        // stage T(it+2) into target buffers (6 loads)
        G2A(0, it + 2, At); G2A(1, it + 2, At);
        G2B(0, it + 2, Btg); G2B(1, it + 2, Btg); G2B(2, it + 2, Btg); G2B(3, it + 2, Btg);

        s16x8 af[2][2], bf[4][2];
#pragma unroll
        for (int mi = 0; mi < 2; ++mi) {
            int rb = (wm + mi * 16 + lm) * 64;
            af[mi][0] = *(const s16x8*)&Ac[rb + kc0];
            af[mi][1] = *(const s16x8*)&Ac[rb + kc1];
        }
#pragma unroll
        for (int ni = 0; ni < 4; ++ni) {
            int rb = (wn + ni * 16 + lm) * 64;
            bf[ni][0] = *(const s16x8*)&Bc[rb + kc0];
            bf[ni][1] = *(const s16x8*)&Bc[rb + kc1];
        }
        __builtin_amdgcn_s_setprio(1);
#pragma unroll
        for (int mi = 0; mi < 2; ++mi)
#pragma unroll
            for (int ni = 0; ni < 4; ++ni) {
                acc[mi][ni] = __builtin_amdgcn_mfma_f32_16x16x32_bf16(
                    af[mi][0], bf[ni][0], acc[mi][ni], 0, 0, 0);
                acc[mi][ni] = __builtin_amdgcn_mfma_f32_16x16x32_bf16(
                    af[mi][1], bf[ni][1], acc[mi][ni], 0, 0, 0);
            }
        __builtin_amdgcn_s_setprio(0);

        u16* tp = Ac; Ac = An; An = At; At = tp;
        tp = Bc; Bc = Bn; Bn = Btg; Btg = tp;
    }
    asm volatile("s_waitcnt vmcnt(0)" ::: "memory");

    int store_f32 = (f == 0);
    int cn = lane & 15, cr = (lane >> 4) * 4;
#pragma unroll
    for (int ni = 0; ni < 4; ++ni) {
        int gn = n0 + wn + ni * 16 + cn;
        float bb = f ? b2f(((const u16*)bias)[gn]) : ((const float*)bias)[gn];
#pragma unroll
        for (int mi = 0; mi < 2; ++mi)
            for (int r = 0; r < 4; ++r) {
                int gm = m0 + wm + mi * 16 + cr + r;
                float v = acc[mi][ni][r] + bb;
                size_t o = (size_t)gm * N + gn;
                if (store_f32) Cf[o] = v;
                else           Cb[o] = f2b(v);
            }
    }
}

// ---- MFMA sparse attention (R9-exact: Qs staging, fixed bounds) ----
#define VP 264
#define PP 264
__global__ __launch_bounds__(256) void k_attn4(const u16* __restrict__ QKV,
                                               u16* __restrict__ AO) {
    int bx = blockIdx.x, h = blockIdx.y, b = blockIdx.z;
    int qb = bx >> 1, sb = bx & 1;
    int t = threadIdx.x, lane = t & 63, wave = t >> 6;
    int lm = lane & 15, q4 = lane >> 4;
    int nstr = qb << 3;
    int nk = nstr + (sb << 6) + 64;     // <= 248
    int r0 = (qb << 7) + (sb << 6);

    __shared__ char smem[79872];
    u16* Vts = (u16*)smem;                       // 64 x 264
    u16* Qs  = (u16*)(smem + 33792);             // 64 x 72
    u16* Ks  = (u16*)(smem + 33792 + 9216);      // 256 x 72
    u16* Ps  = (u16*)(smem + 33792);             // aliases Qs+Ks

    int hm = b * 16 + h;
    const u16* qp = QKV + ((size_t)hm * 2048 + r0) * 64;
    const u16* kp = QKV + ((size_t)(32 + hm) * 2048) * 64;
    const u16* vp = QKV + ((size_t)(64 + hm) * 2048) * 64;

    for (int c = t; c < 512; c += 256) {
        int r = c >> 3, d0 = (c & 7) << 3;
        *(uint4*)&Qs[r * 72 + d0] = *(const uint4*)(qp + c * 8);
    }
    uint4 zz = {0u, 0u, 0u, 0u};
    for (int c = t; c < 2048; c += 256) {
        int i = c >> 3, d0 = (c & 7) << 3;
        uint4 kv = zz;
        if (i < nk) {
            int key = (i < nstr) ? (((i >> 3) << 7) + 120 + (i & 7))
                                 : ((qb << 7) + (i - nstr));
            kv = *(const uint4*)(kp + key * 64 + d0);
        }
        *(uint4*)&Ks[i * 72 + d0] = kv;
    }
    {
        int i0 = (t & 31) * 8, d0 = (t >> 5) * 8;
        u16 m8[8][8];
        for (int r = 0; r < 8; ++r) {
            int i = i0 + r;
            uint4 vv = zz;
            if (i < nk) {
                int key = (i < nstr) ? (((i >> 3) << 7) + 120 + (i & 7))
                                     : ((qb << 7) + (i - nstr));
                vv = *(const uint4*)(vp + key * 64 + d0);
            }
            *(uint4*)m8[r] = vv;
        }
        for (int j = 0; j < 8; ++j) {
            u16 o[8];
            for (int r = 0; r < 8; ++r) o[r] = m8[r][j];
            *(uint4*)&Vts[(d0 + j) * VP + i0] = *(uint4*)o;
        }
    }
    __syncthreads();

    f32x4 acc[16];
    f32x4 z4 = {0.f, 0.f, 0.f, 0.f};
    for (int ni = 0; ni < 16; ++ni) acc[ni] = z4;
    s16x8 af0 = *(const s16x8*)&Qs[(wave * 16 + lm) * 72 + q4 * 8];
    s16x8 af1 = *(const s16x8*)&Qs[(wave * 16 + lm) * 72 + 32 + q4 * 8];
    for (int ni = 0; ni < 16; ++ni) {
        s16x8 bf0 = *(const s16x8*)&Ks[(ni * 16 + lm) * 72 + q4 * 8];
        s16x8 bf1 = *(const s16x8*)&Ks[(ni * 16 + lm) * 72 + 32 + q4 * 8];
        acc[ni] = __builtin_amdgcn_mfma_f32_16x16x32_bf16(af0, bf0, acc[ni], 0, 0, 0);
        acc[ni] = __builtin_amdgcn_mfma_f32_16x16x32_bf16(af1, bf1, acc[ni], 0, 0, 0);
    }
    __syncthreads();

    float mx[4] = {-3e38f, -3e38f, -3e38f, -3e38f};
    for (int ni = 0; ni < 16; ++ni) {
        int i = ni * 16 + lm;
        for (int reg = 0; reg < 4; ++reg) {
            int rl = (sb << 6) + wave * 16 + q4 * 4 + reg;
            bool valid = (i < nstr) || ((i - nstr) <= rl);
            float v = valid ? acc[ni][reg] * 0.125f : -3e38f;
            acc[ni][reg] = v;
            mx[reg] = fmaxf(mx[reg], v);
        }
    }
    for (int reg = 0; reg < 4; ++reg)
        for (int off = 1; off < 16; off <<= 1)
            mx[reg] = fmaxf(mx[reg], __shfl_xor(mx[reg], off, 64));
    float sm[4] = {0.f, 0.f, 0.f, 0.f};
    for (int ni = 0; ni < 16; ++ni)
        for (int reg = 0; reg < 4; ++reg) {
            float e = __expf(acc[ni][reg] - mx[reg]);
            acc[ni][reg] = e;
            sm[reg] += e;
        }
    for (int reg = 0; reg < 4; ++reg)
        for (int off = 1; off < 16; off <<= 1)
            sm[reg] += __shfl_xor(sm[reg], off, 64);
    float inv[4];
    for (int reg = 0; reg < 4; ++reg) inv[reg] = 1.f / sm[reg];

    for (int ni = 0; ni < 16; ++ni) {
        int i = ni * 16 + lm;
        for (int reg = 0; reg < 4; ++reg)
            Ps[(wave * 16 + q4 * 4 + reg) * PP + i] = f2b(acc[ni][reg]);
    }
    __syncthreads();

    f32x4 acc2[4];
    for (int ni2 = 0; ni2 < 4; ++ni2) acc2[ni2] = z4;
    for (int k0 = 0; k0 < 256; k0 += 32) {
        s16x8 pf = *(const s16x8*)&Ps[(wave * 16 + lm) * PP + k0 + q4 * 8];
        for (int ni2 = 0; ni2 < 4; ++ni2) {
            s16x8 vf = *(const s16x8*)&Vts[(ni2 * 16 + lm) * VP + k0 + q4 * 8];
            acc2[ni2] = __builtin_amdgcn_mfma_f32_16x16x32_bf16(pf, vf, acc2[ni2], 0, 0, 0);
        }
    }
    int srow = r0 + wave * 16 + q4 * 4;
    for (int ni2 = 0; ni2 < 4; ++ni2)
        for (int reg = 0; reg < 4; ++reg) {
            size_t o = ((size_t)(b * SDIM + srow + reg)) * EDIM + h * 64 + ni2 * 16 + lm;
            AO[o] = f2b(acc2[ni2][reg] * inv[reg]);
        }
}

extern "C" void kernel_launch(void* const* d_in, const int* in_sizes, int n_in,
                              void* d_out, int out_size, void* d_ws, size_t ws_size,
                              hipStream_t stream) {
    const void* X  = d_in[0];
    const void* Wa = d_in[1];
    const void* ba = d_in[2];
    const void* Wp = d_in[3];
    const void* bp = d_in[4];

    char* w = (char*)d_ws;
    u16* Xb   = (u16*)(w);
    u16* WtA  = (u16*)(w + 8388608);
    u16* WtP  = (u16*)(w + 14680064);
    u16* QKVh = (u16*)(w + 16777216);
    u16* AO   = (u16*)(w + 41943040);

    k_prep<<<dim3(48, 16, 3), 256, 0, stream>>>(X, Wa, Wp, Xb, WtA, WtP);
    k_gemm1<<<dim3(256), 512, 0, stream>>>((const u16*)X, Xb, WtA, ba, QKVh);
    k_attn4<<<dim3(32, 16, 2), 256, 0, stream>>>(QKVh, AO);
    k_gemm2<<<dim3(8, 64), 256, 0, stream>>>((const u16*)X, AO, WtP, bp,
                                             (u16*)d_out, (float*)d_out);
}

// Round 11
// 151.046 us; speedup vs baseline: 1.0623x; 1.0152x over previous
//
#include <hip/hip_runtime.h>
#include <hip/hip_bf16.h>
#include <stdint.h>

typedef unsigned short u16;
typedef uint32_t u32;
typedef short s16x8 __attribute__((ext_vector_type(8)));
typedef float f32x4 __attribute__((ext_vector_type(4)));

#define SDIM 2048
#define EDIM 1024

static __device__ __forceinline__ float b2f(u16 v) {
    union { float f; u32 u; } c; c.u = ((u32)v) << 16; return c.f;
}
static __device__ __forceinline__ u16 f2b(float f) {
    union { float f; u32 u; } c; c.f = f;
    u32 u = c.u;
    u32 r = (u + 0x7FFFu + ((u >> 16) & 1u)) >> 16;
    return (u16)r;
}
static __device__ __forceinline__ void gll16(const u16* g, u16* l) {
    __builtin_amdgcn_global_load_lds(
        (const __attribute__((address_space(1))) void*)g,
        (__attribute__((address_space(3))) void*)l, 16, 0, 0);
}

// per-wave dtype sniff (verified R1/R5)
static __device__ __forceinline__ int sniff_bf16(const u16* __restrict__ x) {
    u16 v = x[(threadIdx.x & 63) * 2];
    int e = (v >> 7) & 0xFF;
    unsigned long long m = __ballot(e >= 90 && e <= 144);
    return __popcll(m) >= 48;
}

// ---- fused prep: z=0 Wa^T, z=1 Wp^T (LDS-tiled), z=2 X convert (fp32 path) ----
__global__ __launch_bounds__(256) void k_prep(
    const void* __restrict__ X, const void* __restrict__ Wa,
    const void* __restrict__ Wp, u16* __restrict__ Xb,
    u16* __restrict__ WtA, u16* __restrict__ WtP) {
    int f = sniff_bf16((const u16*)X);
    int z = blockIdx.z;
    int t = threadIdx.x;
    if (z == 2) {
        if (f) return;
        const float* s = (const float*)X;
        int bid = blockIdx.y * 48 + blockIdx.x;
        for (int c = bid; c < 2048; c += 768) {
            long i = ((long)c * 256 + t) * 8;
            u16 o[8];
            for (int j = 0; j < 8; ++j) o[j] = f2b(s[i + j]);
            *(uint4*)&Xb[i] = *(uint4*)o;
        }
        return;
    }
    if (z == 1 && blockIdx.x >= 16) return;
    const void* src = z ? Wp : Wa;
    u16* dst = z ? WtP : WtA;
    int Nsrc = z ? 1024 : 3072;
    int n0 = blockIdx.x * 64, k0 = blockIdx.y * 64;
    __shared__ u16 L[64 * 72];
    int r = t >> 2, c0 = (t & 3) * 16;
    u16 val[16];
    if (f) {
        const u16* s = (const u16*)src + (size_t)(k0 + r) * Nsrc + n0 + c0;
        *(uint4*)&val[0] = *(const uint4*)s;
        *(uint4*)&val[8] = *(const uint4*)(s + 8);
    } else {
        const float* s = (const float*)src + (size_t)(k0 + r) * Nsrc + n0 + c0;
        for (int j = 0; j < 16; ++j) val[j] = f2b(s[j]);
    }
    for (int j = 0; j < 16; ++j) L[(c0 + j) * 72 + r] = val[j];
    __syncthreads();
    uint4 o0 = *(const uint4*)&L[r * 72 + c0];
    uint4 o1 = *(const uint4*)&L[r * 72 + c0 + 8];
    u16* d = dst + (size_t)(n0 + r) * 1024 + k0 + c0;
    *(uint4*)d = o0;
    *(uint4*)(d + 8) = o1;
}

// ---- GEMM1 (R9-proven): 256x192, BK=64, 8 waves, dbuf-2, 4-phase,
// 256 blocks = 1/CU, counted vmcnt(4), rule-#21 swizzle, LDS-bounce epilogue ----
#define ASL(p) (SH + (p) * 16384)
#define BSL(p) (SH + 32768 + (p) * 12288)
#define STA6(s, Tn) gll16(Asrc + (size_t)(s) * 64 * 1024 + ((Tn) & 15) * 64, \
                          &ASL((Tn) & 1)[(((s) * 64) + wave * 8) * 64])
#define STB6(s, Tn) gll16(Bsrc + (size_t)(s) * 64 * 1024 + ((Tn) & 15) * 64, \
                          &BSL((Tn) & 1)[(((s) * 64) + wave * 8) * 64])

__global__ __launch_bounds__(512, 2) void k_gemm1(
    const u16* __restrict__ Xraw, const u16* __restrict__ Xb,
    const u16* __restrict__ Bt, const void* __restrict__ bias,
    u16* __restrict__ C) {
    const int K = 1024;
    __shared__ u16 SH[57344];   // 112 KiB: A dbuf 2x16384, B dbuf 2x12288
    int f = sniff_bf16(Xraw);
    const u16* A = f ? Xraw : Xb;
    int t = threadIdx.x, wave = t >> 6, lane = t & 63;
    int bid = blockIdx.x;
    int swz = (bid & 7) * 32 + (bid >> 3);
    int bx = swz & 15, by = swz >> 4;
    int m0 = by * 256, n0 = bx * 192;
    int wr = wave >> 2, wc = wave & 3;
    int lm = lane & 15, q4 = lane >> 4;
    int l8 = lane >> 3, l7 = lane & 7;
    int scol = (l7 ^ l8) * 8;
    const u16* Asrc = A  + (size_t)(m0 + wave * 8 + l8) * K + scol;
    const u16* Bsrc = Bt + (size_t)(n0 + wave * 8 + l8) * K + scol;
    int kc0 = (q4 ^ (lm & 7)) * 8;
    int kc1 = ((4 + q4) ^ (lm & 7)) * 8;

    f32x4 acc[8][3];
    f32x4 z = {0.f, 0.f, 0.f, 0.f};
#pragma unroll
    for (int mi = 0; mi < 8; ++mi)
#pragma unroll
        for (int ni = 0; ni < 3; ++ni) acc[mi][ni] = z;

    STA6(0, 0); STA6(1, 0); STA6(2, 0); STA6(3, 0);
    STB6(0, 0); STB6(1, 0); STB6(2, 0);
    STA6(0, 1); STA6(1, 1); STA6(2, 1); STA6(3, 1);

    s16x8 afr[8][2], bfr[3][2];

    for (int T = 0; T < 16; ++T) {
        int p = T & 1;
        asm volatile("s_waitcnt vmcnt(4)\n\ts_barrier" ::: "memory");
        // ph0
#pragma unroll
        for (int mi = 0; mi < 4; ++mi) {
            int rb = (wr * 128 + mi * 16 + lm) * 64;
            afr[mi][0] = *(const s16x8*)&ASL(p)[rb + kc0];
            afr[mi][1] = *(const s16x8*)&ASL(p)[rb + kc1];
        }
#pragma unroll
        for (int ni = 0; ni < 2; ++ni) {
            int rb = (wc * 48 + ni * 16 + lm) * 64;
            bfr[ni][0] = *(const s16x8*)&BSL(p)[rb + kc0];
            bfr[ni][1] = *(const s16x8*)&BSL(p)[rb + kc1];
        }
        STB6(0, T + 1);
        __builtin_amdgcn_s_setprio(1);
#pragma unroll
        for (int mi = 0; mi < 4; ++mi)
#pragma unroll
            for (int ni = 0; ni < 2; ++ni) {
                acc[mi][ni] = __builtin_amdgcn_mfma_f32_16x16x32_bf16(
                    afr[mi][0], bfr[ni][0], acc[mi][ni], 0, 0, 0);
                acc[mi][ni] = __builtin_amdgcn_mfma_f32_16x16x32_bf16(
                    afr[mi][1], bfr[ni][1], acc[mi][ni], 0, 0, 0);
            }
        __builtin_amdgcn_s_setprio(0);
        asm volatile("s_barrier" ::: "memory");
        // ph1
#pragma unroll
        for (int mi = 4; mi < 8; ++mi) {
            int rb = (wr * 128 + mi * 16 + lm) * 64;
            afr[mi][0] = *(const s16x8*)&ASL(p)[rb + kc0];
            afr[mi][1] = *(const s16x8*)&ASL(p)[rb + kc1];
        }
        {
            int rb = (wc * 48 + 32 + lm) * 64;
            bfr[2][0] = *(const s16x8*)&BSL(p)[rb + kc0];
            bfr[2][1] = *(const s16x8*)&BSL(p)[rb + kc1];
        }
        STB6(1, T + 1); STB6(2, T + 1);
        __builtin_amdgcn_s_setprio(1);
#pragma unroll
        for (int mi = 4; mi < 8; ++mi) {
            acc[mi][2] = __builtin_amdgcn_mfma_f32_16x16x32_bf16(
                afr[mi][0], bfr[2][0], acc[mi][2], 0, 0, 0);
            acc[mi][2] = __builtin_amdgcn_mfma_f32_16x16x32_bf16(
                afr[mi][1], bfr[2][1], acc[mi][2], 0, 0, 0);
        }
        __builtin_amdgcn_s_setprio(0);
        asm volatile("s_barrier" ::: "memory");
        // ph2
        STA6(0, T + 2); STA6(1, T + 2);
        __builtin_amdgcn_s_setprio(1);
#pragma unroll
        for (int mi = 0; mi < 4; ++mi) {
            acc[mi][2] = __builtin_amdgcn_mfma_f32_16x16x32_bf16(
                afr[mi][0], bfr[2][0], acc[mi][2], 0, 0, 0);
            acc[mi][2] = __builtin_amdgcn_mfma_f32_16x16x32_bf16(
                afr[mi][1], bfr[2][1], acc[mi][2], 0, 0, 0);
        }
        __builtin_amdgcn_s_setprio(0);
        asm volatile("s_barrier" ::: "memory");
        // ph3
        STA6(2, T + 2); STA6(3, T + 2);
        __builtin_amdgcn_s_setprio(1);
#pragma unroll
        for (int mi = 4; mi < 8; ++mi)
#pragma unroll
            for (int ni = 0; ni < 2; ++ni) {
                acc[mi][ni] = __builtin_amdgcn_mfma_f32_16x16x32_bf16(
                    afr[mi][0], bfr[ni][0], acc[mi][ni], 0, 0, 0);
                acc[mi][ni] = __builtin_amdgcn_mfma_f32_16x16x32_bf16(
                    afr[mi][1], bfr[ni][1], acc[mi][ni], 0, 0, 0);
            }
        __builtin_amdgcn_s_setprio(0);
        asm volatile("s_barrier" ::: "memory");
    }
    asm volatile("s_waitcnt vmcnt(0)" ::: "memory");
    __syncthreads();   // all waves' trailing gll-writes drained before LDS repurpose

    // ---- R9 bounce epilogue ----
    float bb[3];
#pragma unroll
    for (int ni = 0; ni < 3; ++ni) {
        int gn = n0 + wc * 48 + ni * 16 + lm;
        bb[ni] = f ? b2f(((const u16*)bias)[gn]) : ((const float*)bias)[gn];
    }
#pragma unroll
    for (int mi = 0; mi < 8; ++mi)
        for (int r = 0; r < 4; ++r) {
            int row = wr * 128 + mi * 16 + q4 * 4 + r;
#pragma unroll
            for (int ni = 0; ni < 3; ++ni) {
                int ld = wc * 48 + ni * 16 + lm;
                int sl = ld >> 6, d = ld & 63;
                SH[sl * 18432 + row * 72 + d] = f2b(acc[mi][ni][r] + bb[ni]);
            }
        }
    __syncthreads();
    int bB = m0 >> 11, ms = m0 & 2047;
#pragma unroll
    for (int sl = 0; sl < 3; ++sl) {
        int gnb = n0 + sl * 64;
        int kind = gnb >> 10, rem = gnb & 1023;
        int hmh = kind * 32 + (rem >> 6);
        size_t base = ((size_t)(hmh + bB * 16)) * 2048 * 64;
#pragma unroll
        for (int i = 0; i < 4; ++i) {
            int c = t + i * 512;
            int s_ = c >> 3, d0 = (c & 7) * 8;
            uint4 v = *(const uint4*)&SH[sl * 18432 + s_ * 72 + d0];
            *(uint4*)&C[base + (size_t)(ms + s_) * 64 + d0] = v;
        }
    }
}

// ---- GEMM2 (R10-proven): 64x128, BK=64, tri-buffer counted vmcnt(6),
// 16 MFMA / 1 barrier per tile, rule-#21 swizzle ----
#define G2A(s, Tn, dst) gll16(Ap + (size_t)(s) * 32 * 1024 + ((Tn) & 15) * 64, \
                              (dst) + (s) * 2048 + t * 8)
#define G2B(s, Tn, dst) gll16(Bp + (size_t)(s) * 32 * 1024 + ((Tn) & 15) * 64, \
                              (dst) + (s) * 2048 + t * 8)

__global__ __launch_bounds__(256) void k_gemm2(
    const u16* __restrict__ Xraw, const u16* __restrict__ A,
    const u16* __restrict__ Bt, const void* __restrict__ bias,
    u16* __restrict__ Cb, float* __restrict__ Cf) {
    const int K = 1024, N = 1024;
    __shared__ u16 As[3][64 * 64];    // 3 x 8 KiB
    __shared__ u16 Bs[3][128 * 64];   // 3 x 16 KiB
    int f = sniff_bf16(Xraw);
    int t = threadIdx.x, wave = t >> 6, lane = t & 63;
    int m0 = blockIdx.y * 64, n0 = blockIdx.x * 128;
    int wm = (wave >> 1) * 32, wn = (wave & 1) * 64;
    int lm = lane & 15, q4 = lane >> 4;
    int srow = t >> 3, sg = t & 7;
    int scol = (sg ^ (srow & 7)) * 8;
    const u16* Ap = A  + (size_t)(m0 + srow) * K + scol;
    const u16* Bp = Bt + (size_t)(n0 + srow) * K + scol;
    int kc0 = (q4 ^ (lm & 7)) * 8;
    int kc1 = ((4 + q4) ^ (lm & 7)) * 8;

    f32x4 acc[2][4];
    f32x4 z = {0.f, 0.f, 0.f, 0.f};
#pragma unroll
    for (int mi = 0; mi < 2; ++mi)
#pragma unroll
        for (int ni = 0; ni < 4; ++ni) acc[mi][ni] = z;

    G2A(0, 0, &As[0][0]); G2A(1, 0, &As[0][0]);
    G2B(0, 0, &Bs[0][0]); G2B(1, 0, &Bs[0][0]); G2B(2, 0, &Bs[0][0]); G2B(3, 0, &Bs[0][0]);
    G2A(0, 1, &As[1][0]); G2A(1, 1, &As[1][0]);
    G2B(0, 1, &Bs[1][0]); G2B(1, 1, &Bs[1][0]); G2B(2, 1, &Bs[1][0]); G2B(3, 1, &Bs[1][0]);

    u16 *Ac = &As[0][0], *An = &As[1][0], *At = &As[2][0];
    u16 *Bc = &Bs[0][0], *Bn = &Bs[1][0], *Btg = &Bs[2][0];

    for (int it = 0; it < 16; ++it) {
        asm volatile("s_waitcnt vmcnt(6)\n\ts_barrier" ::: "memory");
        G2A(0, it + 2, At); G2A(1, it + 2, At);
        G2B(0, it + 2, Btg); G2B(1, it + 2, Btg); G2B(2, it + 2, Btg); G2B(3, it + 2, Btg);

        s16x8 af[2][2], bf[4][2];
#pragma unroll
        for (int mi = 0; mi < 2; ++mi) {
            int rb = (wm + mi * 16 + lm) * 64;
            af[mi][0] = *(const s16x8*)&Ac[rb + kc0];
            af[mi][1] = *(const s16x8*)&Ac[rb + kc1];
        }
#pragma unroll
        for (int ni = 0; ni < 4; ++ni) {
            int rb = (wn + ni * 16 + lm) * 64;
            bf[ni][0] = *(const s16x8*)&Bc[rb + kc0];
            bf[ni][1] = *(const s16x8*)&Bc[rb + kc1];
        }
        __builtin_amdgcn_s_setprio(1);
#pragma unroll
        for (int mi = 0; mi < 2; ++mi)
#pragma unroll
            for (int ni = 0; ni < 4; ++ni) {
                acc[mi][ni] = __builtin_amdgcn_mfma_f32_16x16x32_bf16(
                    af[mi][0], bf[ni][0], acc[mi][ni], 0, 0, 0);
                acc[mi][ni] = __builtin_amdgcn_mfma_f32_16x16x32_bf16(
                    af[mi][1], bf[ni][1], acc[mi][ni], 0, 0, 0);
            }
        __builtin_amdgcn_s_setprio(0);

        u16* tp = Ac; Ac = An; An = At; At = tp;
        tp = Bc; Bc = Bn; Bn = Btg; Btg = tp;
    }
    asm volatile("s_waitcnt vmcnt(0)" ::: "memory");

    int store_f32 = (f == 0);
    int cn = lane & 15, cr = (lane >> 4) * 4;
#pragma unroll
    for (int ni = 0; ni < 4; ++ni) {
        int gn = n0 + wn + ni * 16 + cn;
        float bb = f ? b2f(((const u16*)bias)[gn]) : ((const float*)bias)[gn];
#pragma unroll
        for (int mi = 0; mi < 2; ++mi)
            for (int r = 0; r < 4; ++r) {
                int gm = m0 + wm + mi * 16 + cr + r;
                float v = acc[mi][ni][r] + bb;
                size_t o = (size_t)gm * N + gn;
                if (store_f32) Cf[o] = v;
                else           Cb[o] = f2b(v);
            }
    }
}

// ---- MFMA sparse attention (R11): K-staging via direct gll16.
// Ks becomes linear [256][64] with rule-#21 swizzle: staging stores
// LDS[i][ch] = global[i][ch ^ (i&7)] (per-lane GLOBAL src carries the
// swizzle + gathered key addressing; LDS dest is wave-linear c*16B);
// QK reads slot q4^(lm&7) / (4+q4)^(lm&7) — identical conflict-0 pattern
// to gemm1 (R5/R6 counters). Zero-fill for rows >= nk DROPPED: the mask
// step assigns -3e38 to every i>=nk position regardless of QK garbage
// (valid iff i<nstr or i-nstr<=rl, and rl < nk-nstr always; NaN-safe
// since the select discards the MFMA value). Masked-lane gll16 (i>=nk)
// simply leaves stale LDS. V/Q staging and PV unchanged. LDS 79.9->75.8K. ----
#define VP 264
#define PP 264
__global__ __launch_bounds__(256) void k_attn4(const u16* __restrict__ QKV,
                                               u16* __restrict__ AO) {
    int bx = blockIdx.x, h = blockIdx.y, b = blockIdx.z;
    int qb = bx >> 1, sb = bx & 1;
    int t = threadIdx.x, lane = t & 63, wave = t >> 6;
    int lm = lane & 15, q4 = lane >> 4;
    int nstr = qb << 3;
    int nk = nstr + (sb << 6) + 64;     // <= 248
    int r0 = (qb << 7) + (sb << 6);

    __shared__ char smem[75776];
    u16* Vts = (u16*)smem;                       // 64 x 264   (33792 B)
    u16* Qs  = (u16*)(smem + 33792);             // 64 x 72    ( 9216 B)
    u16* Ks  = (u16*)(smem + 43008);             // 256 x 64   (32768 B)
    u16* Ps  = (u16*)(smem + 33792);             // 64 x 264 aliases Qs+Ks

    int hm = b * 16 + h;
    const u16* qp = QKV + ((size_t)hm * 2048 + r0) * 64;
    const u16* kp = QKV + ((size_t)(32 + hm) * 2048) * 64;
    const u16* vp = QKV + ((size_t)(64 + hm) * 2048) * 64;

    for (int c = t; c < 512; c += 256) {
        int r = c >> 3, d0 = (c & 7) << 3;
        *(uint4*)&Qs[r * 72 + d0] = *(const uint4*)(qp + c * 8);
    }
    // K staging: direct global->LDS, per-lane gathered+swizzled source
#pragma unroll
    for (int j = 0; j < 8; ++j) {
        int c = t + j * 256;
        int i = c >> 3, ch = c & 7;
        int key = (i < nstr) ? (((i >> 3) << 7) + 120 + (i & 7))
                             : ((qb << 7) + (i - nstr));
        if (i < nk)
            gll16(kp + key * 64 + ((ch ^ (i & 7)) << 3),
                  &Ks[(wave * 64 + j * 256) * 8]);
    }
    uint4 zz = {0u, 0u, 0u, 0u};
    {
        int i0 = (t & 31) * 8, d0 = (t >> 5) * 8;
        u16 m8[8][8];
        for (int r = 0; r < 8; ++r) {
            int i = i0 + r;
            uint4 vv = zz;
            if (i < nk) {
                int key = (i < nstr) ? (((i >> 3) << 7) + 120 + (i & 7))
                                     : ((qb << 7) + (i - nstr));
                vv = *(const uint4*)(vp + key * 64 + d0);
            }
            *(uint4*)m8[r] = vv;
        }
        for (int j = 0; j < 8; ++j) {
            u16 o[8];
            for (int r = 0; r < 8; ++r) o[r] = m8[r][j];
            *(uint4*)&Vts[(d0 + j) * VP + i0] = *(uint4*)o;
        }
    }
    __syncthreads();

    f32x4 acc[16];
    f32x4 z4 = {0.f, 0.f, 0.f, 0.f};
    for (int ni = 0; ni < 16; ++ni) acc[ni] = z4;
    s16x8 af0 = *(const s16x8*)&Qs[(wave * 16 + lm) * 72 + q4 * 8];
    s16x8 af1 = *(const s16x8*)&Qs[(wave * 16 + lm) * 72 + 32 + q4 * 8];
    int ks0 = (q4 ^ (lm & 7)) << 3;
    int ks1 = ((4 + q4) ^ (lm & 7)) << 3;
    for (int ni = 0; ni < 16; ++ni) {
        int rb = (ni * 16 + lm) * 64;
        s16x8 bf0 = *(const s16x8*)&Ks[rb + ks0];
        s16x8 bf1 = *(const s16x8*)&Ks[rb + ks1];
        acc[ni] = __builtin_amdgcn_mfma_f32_16x16x32_bf16(af0, bf0, acc[ni], 0, 0, 0);
        acc[ni] = __builtin_amdgcn_mfma_f32_16x16x32_bf16(af1, bf1, acc[ni], 0, 0, 0);
    }
    __syncthreads();

    float mx[4] = {-3e38f, -3e38f, -3e38f, -3e38f};
    for (int ni = 0; ni < 16; ++ni) {
        int i = ni * 16 + lm;
        for (int reg = 0; reg < 4; ++reg) {
            int rl = (sb << 6) + wave * 16 + q4 * 4 + reg;
            bool valid = (i < nstr) || ((i - nstr) <= rl);
            float v = valid ? acc[ni][reg] * 0.125f : -3e38f;
            acc[ni][reg] = v;
            mx[reg] = fmaxf(mx[reg], v);
        }
    }
    for (int reg = 0; reg < 4; ++reg)
        for (int off = 1; off < 16; off <<= 1)
            mx[reg] = fmaxf(mx[reg], __shfl_xor(mx[reg], off, 64));
    float sm[4] = {0.f, 0.f, 0.f, 0.f};
    for (int ni = 0; ni < 16; ++ni)
        for (int reg = 0; reg < 4; ++reg) {
            float e = __expf(acc[ni][reg] - mx[reg]);
            acc[ni][reg] = e;
            sm[reg] += e;
        }
    for (int reg = 0; reg < 4; ++reg)
        for (int off = 1; off < 16; off <<= 1)
            sm[reg] += __shfl_xor(sm[reg], off, 64);
    float inv[4];
    for (int reg = 0; reg < 4; ++reg) inv[reg] = 1.f / sm[reg];

    for (int ni = 0; ni < 16; ++ni) {
        int i = ni * 16 + lm;
        for (int reg = 0; reg < 4; ++reg)
            Ps[(wave * 16 + q4 * 4 + reg) * PP + i] = f2b(acc[ni][reg]);
    }
    __syncthreads();

    f32x4 acc2[4];
    for (int ni2 = 0; ni2 < 4; ++ni2) acc2[ni2] = z4;
    for (int k0 = 0; k0 < 256; k0 += 32) {
        s16x8 pf = *(const s16x8*)&Ps[(wave * 16 + lm) * PP + k0 + q4 * 8];
        for (int ni2 = 0; ni2 < 4; ++ni2) {
            s16x8 vf = *(const s16x8*)&Vts[(ni2 * 16 + lm) * VP + k0 + q4 * 8];
            acc2[ni2] = __builtin_amdgcn_mfma_f32_16x16x32_bf16(pf, vf, acc2[ni2], 0, 0, 0);
        }
    }
    int srow = r0 + wave * 16 + q4 * 4;
    for (int ni2 = 0; ni2 < 4; ++ni2)
        for (int reg = 0; reg < 4; ++reg) {
            size_t o = ((size_t)(b * SDIM + srow + reg)) * EDIM + h * 64 + ni2 * 16 + lm;
            AO[o] = f2b(acc2[ni2][reg] * inv[reg]);
        }
}

extern "C" void kernel_launch(void* const* d_in, const int* in_sizes, int n_in,
                              void* d_out, int out_size, void* d_ws, size_t ws_size,
                              hipStream_t stream) {
    const void* X  = d_in[0];
    const void* Wa = d_in[1];
    const void* ba = d_in[2];
    const void* Wp = d_in[3];
    const void* bp = d_in[4];

    char* w = (char*)d_ws;
    u16* Xb   = (u16*)(w);
    u16* WtA  = (u16*)(w + 8388608);
    u16* WtP  = (u16*)(w + 14680064);
    u16* QKVh = (u16*)(w + 16777216);
    u16* AO   = (u16*)(w + 41943040);

    k_prep<<<dim3(48, 16, 3), 256, 0, stream>>>(X, Wa, Wp, Xb, WtA, WtP);
    k_gemm1<<<dim3(256), 512, 0, stream>>>((const u16*)X, Xb, WtA, ba, QKVh);
    k_attn4<<<dim3(32, 16, 2), 256, 0, stream>>>(QKVh, AO);
    k_gemm2<<<dim3(8, 64), 256, 0, stream>>>((const u16*)X, AO, WtP, bp,
                                             (u16*)d_out, (float*)d_out);
}